// Round 18
// baseline (284.307 us; speedup 1.0000x reference)
//
#include <hip/hip_runtime.h>
#include <cstdint>
#include <cstddef>

#define N_NODES 100000
#define N_EDGES 1600000
#define HD 128
#define OUTC 64
#define WDIM 512
#define RANKK 10
#define SLOPE 0.01f
#define CAP 32
#define NBUCK ((N_NODES + 255)/256)          // 391 buckets of 256 nodes
#define BCAP 6144                             // entries per bucket region (mean 4096)
#define CHUNK 2048
#define NCH ((N_EDGES + CHUNK - 1)/CHUNK)     // 782

typedef __attribute__((ext_vector_type(8))) short bf16x8;
typedef __attribute__((ext_vector_type(4))) float f32x4;
typedef __attribute__((ext_vector_type(2))) float f32x2;

static __device__ __forceinline__ float lrelu(float v){ return v >= 0.f ? v : SLOPE*v; }
static __device__ __forceinline__ uint32_t bf16rne(float f){
  uint32_t b = __float_as_uint(f);
  return (b + 0x7FFFu + ((b >> 16) & 1u)) >> 16;
}

// ---------------- styles ----------------
__global__ void k_styles(const float* __restrict__ w,
                         const float* __restrict__ a0w, const float* __restrict__ a0b,
                         const float* __restrict__ a1w, const float* __restrict__ a1b,
                         float* __restrict__ st0, float* __restrict__ st1){
  int j = blockIdx.x*blockDim.x + threadIdx.x;
  if (j < 2560){
    float s = a0b[j];
    for (int k=0;k<WDIM;k++) s += w[k]*a0w[k*2560 + j];
    st0[j] = s;
  } else if (j < 2560+1920){
    int jj = j - 2560;
    float s = a1b[jj];
    for (int k=0;k<WDIM;k++) s += w[WDIM + k]*a1w[k*1920 + jj];
    st1[jj] = s;
  }
}

// ---------------- modulated + row-normalized weight, stored TRANSPOSED: wt[k][n] ----
__global__ void k_wmod(const float* __restrict__ st, const float* __restrict__ wgt,
                       float* __restrict__ wt, int c_out){
  int o = blockIdx.x, i = threadIdx.x;
  float mod = 0.f;
  #pragma unroll
  for (int r=0;r<RANKK;r++) mod += st[o*RANKK + r] * st[c_out*RANKK + r*HD + i];
  mod *= 0.31622776601683794f;
  float wv = wgt[o*HD + i] * (mod + 1.f);
  float sq = wv*wv;
  #pragma unroll
  for (int d=1; d<64; d<<=1) sq += __shfl_xor(sq, d, 64);
  __shared__ float red[2];
  if ((i & 63) == 0) red[i>>6] = sq;
  __syncthreads();
  float norm = sqrtf(red[0] + red[1]) + 1e-8f;
  wt[i*c_out + o] = wv / norm;
}

// ---------------- M2 = node_w @ (I + cat2) ; biasv = cat1_b + cat2_b + node_b@(I+cat2)
__global__ void k_m2bias(const float* __restrict__ node_w, const float* __restrict__ node_b,
                         const float* __restrict__ cat2_w, const float* __restrict__ cat1_b,
                         const float* __restrict__ cat2_b,
                         float* __restrict__ M2, float* __restrict__ biasv){
  int i = threadIdx.x;
  int k = blockIdx.x;
  if (k < HD){
    float s = node_w[k*HD + i];
    for (int j=0;j<HD;j++) s += node_w[k*HD + j]*cat2_w[j*HD + i];
    M2[k*HD + i] = s;
  } else {
    float s = cat1_b[i] + cat2_b[i] + node_b[i];
    for (int j=0;j<HD;j++) s += node_b[j]*cat2_w[j*HD + i];
    biasv[i] = s;
  }
}

// ---------------- pack B [K][Ncols] f32 -> bf16 MFMA fragments ----------------
__global__ void k_pack(const float* __restrict__ src, int K, int Ncols, int addI,
                       uint32_t* __restrict__ dst){
  int KTn = K >> 5;
  int kt = blockIdx.x % KTn, nt = blockIdx.x / KTn;
  int lane = threadIdx.x;
  int col = nt*16 + (lane & 15);
  uint32_t o[4];
  #pragma unroll
  for (int jj=0;jj<4;jj++){
    int k0 = kt*32 + (lane>>4)*8 + 2*jj;
    float v0 = src[(size_t)k0*Ncols + col]     + ((addI && k0   == col) ? 1.f : 0.f);
    float v1 = src[(size_t)(k0+1)*Ncols + col] + ((addI && k0+1 == col) ? 1.f : 0.f);
    o[jj] = bf16rne(v0) | (bf16rne(v1) << 16);
  }
  ((uint4*)dst)[blockIdx.x*64 + lane] = make_uint4(o[0], o[1], o[2], o[3]);
}

// ---------------- elw f32 -> fp8 e4m3 packed (4 per u32) ----------------
__global__ void k_cvt(const float* __restrict__ elw, uint32_t* __restrict__ elwf8){
  int i = blockIdx.x*blockDim.x + threadIdx.x;
  if (i < N_NODES*(HD/4)){
    float4 v = ((const float4*)elw)[i];
    int r = 0;
    r = __builtin_amdgcn_cvt_pk_fp8_f32(v.x, v.y, r, false);
    r = __builtin_amdgcn_cvt_pk_fp8_f32(v.z, v.w, r, true);
    elwf8[i] = (uint32_t)r;
  }
}

// ---------------- bcur init ----------------
__global__ void k_binit(int* __restrict__ bcur){
  int b = blockIdx.x*blockDim.x + threadIdx.x;
  if (b < NBUCK) bcur[b] = b*BCAP;
}

// ---------------- P1: chunk -> LDS counting sort by bucket -> grouped flush ----------
__global__ __launch_bounds__(256) void k_bucketize(const int* __restrict__ ei,
                                                   const float* __restrict__ ew,
                                                   int* __restrict__ bcur,
                                                   int2* __restrict__ epair,
                                                   int* __restrict__ cnt,
                                                   int4* __restrict__ ovf){
  __shared__ int2 ed[CHUNK];
  __shared__ unsigned short bkt[CHUNK];
  __shared__ unsigned short sidx[CHUNK];
  __shared__ int sa[512], sb[512];
  __shared__ int off[NBUCK], pcur[NBUCK], gbase[NBUCK];
  const int tid = threadIdx.x;
  const int e0 = blockIdx.x * CHUNK;
  const int ne = min(CHUNK, N_EDGES - e0);

  sa[tid] = 0; sa[tid+256] = 0;
  __syncthreads();
  for (int i=tid; i<ne; i+=256){
    int src = ei[e0+i], dst = ei[N_EDGES+e0+i];
    ed[i]  = make_int2(src | ((dst & 255) << 17), __float_as_int(ew[e0+i]));
    int b = dst >> 8;
    bkt[i] = (unsigned short)b;
    atomicAdd(&sa[b], 1);
  }
  __syncthreads();
  int c0 = sa[tid], c1 = sa[tid+256];
  int* cur = sa; int* oth = sb;
  for (int d=1; d<512; d<<=1){
    int v0 = cur[tid]     + (tid     >= d ? cur[tid-d]     : 0);
    int v1 = cur[tid+256] + (tid+256 >= d ? cur[tid+256-d] : 0);
    oth[tid] = v0; oth[tid+256] = v1;
    __syncthreads();
    int* t_ = cur; cur = oth; oth = t_;
  }
  off[tid] = cur[tid] - c0;  pcur[tid] = cur[tid] - c0;
  if (tid+256 < NBUCK){ off[tid+256] = cur[tid+256] - c1; pcur[tid+256] = cur[tid+256] - c1; }
  __syncthreads();
  int rot = (blockIdx.x * 73) % NBUCK;
  for (int k=tid; k<NBUCK; k+=256){
    int b = k + rot; if (b >= NBUCK) b -= NBUCK;
    int cb = cur[b] - off[b];
    if (cb > 0) gbase[b] = atomicAdd(&bcur[b], cb);
  }
  __syncthreads();
  for (int i=tid; i<ne; i+=256){
    int s = atomicAdd(&pcur[bkt[i]], 1);
    sidx[s] = (unsigned short)i;
  }
  __syncthreads();
  for (int j=tid; j<ne; j+=256){
    int i = sidx[j];
    int b = bkt[i];
    int addr = gbase[b] + (j - off[b]);
    if (addr < (b+1)*BCAP){
      epair[addr] = ed[i];
    } else {
      int oi = atomicAdd(&cnt[N_NODES], 1);
      ovf[oi] = make_int4(ed[i].x & 0x1FFFF, b*256 + ((ed[i].x>>17)&255), ed[i].y, 0);
    }
  }
}

// ---------------- P2: bucket region -> per-node slots ----------------
__global__ __launch_bounds__(256) void k_slotfill(const int* __restrict__ bcur,
                                                  const int2* __restrict__ epair,
                                                  int* __restrict__ cnt,
                                                  uint32_t* __restrict__ eslot,
                                                  int4* __restrict__ ovf){
  __shared__ int lcnt[256];
  const int tid = threadIdx.x;
  const int b = blockIdx.x;
  const int n0 = b*256;
  const int2* reg = epair + (size_t)b*BCAP;
  const int count = min(bcur[b], (b+1)*BCAP) - b*BCAP;
  lcnt[tid] = 0;
  __syncthreads();
  for (int j=tid; j<count; j+=256){
    int2 rec = reg[j];
    int ldst = (rec.x >> 17) & 255;
    int pos = atomicAdd(&lcnt[ldst], 1);
    if (pos < CAP){
      uint32_t wb = (uint32_t)rec.y;
      uint32_t wenc = ((wb + 0x8000u) >> 16) & 0x7FFFu;
      eslot[(size_t)(n0+ldst)*CAP + pos] = (uint32_t)(rec.x & 0x1FFFF) | (wenc << 17);
    } else {
      int oi = atomicAdd(&cnt[N_NODES], 1);
      ovf[oi] = make_int4(rec.x & 0x1FFFF, n0 + ldst, rec.y, 0);
    }
  }
  __syncthreads();
  if (n0 + tid < N_NODES) cnt[n0 + tid] = lcnt[tid];
}

// ---------------- per-node gather core (fp8 rows, 8-deep + masked tail) ----------
static __device__ __forceinline__ float2 gather_node(int node, int lane,
    const int* __restrict__ cnt, const uint32_t* __restrict__ eslot,
    const unsigned short* __restrict__ e8, const int4* __restrict__ ovf){
  const uint32_t* base = eslot + (size_t)node*CAP;
  int c = cnt[node];
  int cc = min(c, CAP);
  float sx = 0.f, sy = 0.f;
  int e = 0;
  for (; e + 8 <= cc; e += 8){
    uint32_t p0 = base[e],   p1 = base[e+1], p2 = base[e+2], p3 = base[e+3];
    uint32_t p4 = base[e+4], p5 = base[e+5], p6 = base[e+6], p7 = base[e+7];
    unsigned short v0 = e8[(p0 & 0x1FFFFu)*64u + lane];
    unsigned short v1 = e8[(p1 & 0x1FFFFu)*64u + lane];
    unsigned short v2 = e8[(p2 & 0x1FFFFu)*64u + lane];
    unsigned short v3 = e8[(p3 & 0x1FFFFu)*64u + lane];
    unsigned short v4 = e8[(p4 & 0x1FFFFu)*64u + lane];
    unsigned short v5 = e8[(p5 & 0x1FFFFu)*64u + lane];
    unsigned short v6 = e8[(p6 & 0x1FFFFu)*64u + lane];
    unsigned short v7 = e8[(p7 & 0x1FFFFu)*64u + lane];
    float w0 = __uint_as_float((p0 >> 17) << 16), w1 = __uint_as_float((p1 >> 17) << 16);
    float w2 = __uint_as_float((p2 >> 17) << 16), w3 = __uint_as_float((p3 >> 17) << 16);
    float w4 = __uint_as_float((p4 >> 17) << 16), w5 = __uint_as_float((p5 >> 17) << 16);
    float w6 = __uint_as_float((p6 >> 17) << 16), w7 = __uint_as_float((p7 >> 17) << 16);
    f32x2 f0 = __builtin_amdgcn_cvt_pk_f32_fp8((int)v0, false);
    f32x2 f1 = __builtin_amdgcn_cvt_pk_f32_fp8((int)v1, false);
    f32x2 f2 = __builtin_amdgcn_cvt_pk_f32_fp8((int)v2, false);
    f32x2 f3 = __builtin_amdgcn_cvt_pk_f32_fp8((int)v3, false);
    f32x2 f4 = __builtin_amdgcn_cvt_pk_f32_fp8((int)v4, false);
    f32x2 f5 = __builtin_amdgcn_cvt_pk_f32_fp8((int)v5, false);
    f32x2 f6 = __builtin_amdgcn_cvt_pk_f32_fp8((int)v6, false);
    f32x2 f7 = __builtin_amdgcn_cvt_pk_f32_fp8((int)v7, false);
    sx += f0.x*w0;  sy += f0.y*w0;
    sx += f1.x*w1;  sy += f1.y*w1;
    sx += f2.x*w2;  sy += f2.y*w2;
    sx += f3.x*w3;  sy += f3.y*w3;
    sx += f4.x*w4;  sy += f4.y*w4;
    sx += f5.x*w5;  sy += f5.y*w5;
    sx += f6.x*w6;  sy += f6.y*w6;
    sx += f7.x*w7;  sy += f7.y*w7;
  }
  if (e < cc){
    int last = cc - 1;
    int i0 = min(e+0, last), i1 = min(e+1, last), i2 = min(e+2, last), i3 = min(e+3, last);
    int i4 = min(e+4, last), i5 = min(e+5, last), i6 = min(e+6, last), i7 = min(e+7, last);
    uint32_t p0 = base[i0], p1 = base[i1], p2 = base[i2], p3 = base[i3];
    uint32_t p4 = base[i4], p5 = base[i5], p6 = base[i6], p7 = base[i7];
    unsigned short v0 = e8[(p0 & 0x1FFFFu)*64u + lane];
    unsigned short v1 = e8[(p1 & 0x1FFFFu)*64u + lane];
    unsigned short v2 = e8[(p2 & 0x1FFFFu)*64u + lane];
    unsigned short v3 = e8[(p3 & 0x1FFFFu)*64u + lane];
    unsigned short v4 = e8[(p4 & 0x1FFFFu)*64u + lane];
    unsigned short v5 = e8[(p5 & 0x1FFFFu)*64u + lane];
    unsigned short v6 = e8[(p6 & 0x1FFFFu)*64u + lane];
    unsigned short v7 = e8[(p7 & 0x1FFFFu)*64u + lane];
    float w0 = (e+0 < cc) ? __uint_as_float((p0 >> 17) << 16) : 0.f;
    float w1 = (e+1 < cc) ? __uint_as_float((p1 >> 17) << 16) : 0.f;
    float w2 = (e+2 < cc) ? __uint_as_float((p2 >> 17) << 16) : 0.f;
    float w3 = (e+3 < cc) ? __uint_as_float((p3 >> 17) << 16) : 0.f;
    float w4 = (e+4 < cc) ? __uint_as_float((p4 >> 17) << 16) : 0.f;
    float w5 = (e+5 < cc) ? __uint_as_float((p5 >> 17) << 16) : 0.f;
    float w6 = (e+6 < cc) ? __uint_as_float((p6 >> 17) << 16) : 0.f;
    float w7 = (e+7 < cc) ? __uint_as_float((p7 >> 17) << 16) : 0.f;
    f32x2 f0 = __builtin_amdgcn_cvt_pk_f32_fp8((int)v0, false);
    f32x2 f1 = __builtin_amdgcn_cvt_pk_f32_fp8((int)v1, false);
    f32x2 f2 = __builtin_amdgcn_cvt_pk_f32_fp8((int)v2, false);
    f32x2 f3 = __builtin_amdgcn_cvt_pk_f32_fp8((int)v3, false);
    f32x2 f4 = __builtin_amdgcn_cvt_pk_f32_fp8((int)v4, false);
    f32x2 f5 = __builtin_amdgcn_cvt_pk_f32_fp8((int)v5, false);
    f32x2 f6 = __builtin_amdgcn_cvt_pk_f32_fp8((int)v6, false);
    f32x2 f7 = __builtin_amdgcn_cvt_pk_f32_fp8((int)v7, false);
    sx += f0.x*w0;  sy += f0.y*w0;
    sx += f1.x*w1;  sy += f1.y*w1;
    sx += f2.x*w2;  sy += f2.y*w2;
    sx += f3.x*w3;  sy += f3.y*w3;
    sx += f4.x*w4;  sy += f4.y*w4;
    sx += f5.x*w5;  sy += f5.y*w5;
    sx += f6.x*w6;  sy += f6.y*w6;
    sx += f7.x*w7;  sy += f7.y*w7;
  }
  int ocnt = cnt[N_NODES];
  if (ocnt > 0){
    for (int i = 0; i < ocnt; ++i){
      int4 o = ovf[i];
      if (o.y == node){
        float wv = __int_as_float(o.z);
        f32x2 f = __builtin_amdgcn_cvt_pk_f32_fp8((int)e8[(uint32_t)o.x*64u + lane], false);
        sx += f.x * wv;
        sy += f.y * wv;
      }
    }
  }
  return make_float2(sx, sy);
}

// ---------------- fused: gather + 4-GEMM chain (bf16 MFMA, hi/lo compensated) --------
__global__ __launch_bounds__(512, 4) void k_fused(
    const int* __restrict__ cnt, const uint32_t* __restrict__ eslot,
    const uint32_t* __restrict__ elwf8, const float* __restrict__ elb,
    const int4* __restrict__ ovf, const float* __restrict__ x,
    const uint32_t* __restrict__ B1pk, const uint32_t* __restrict__ B2pk,
    const uint32_t* __restrict__ B3pk, const uint32_t* __restrict__ B4pk,
    const float* __restrict__ biasv, const float* __restrict__ sb0,
    const float* __restrict__ sb1, float* __restrict__ outp){
  __shared__ uint32_t lds[16384];                 // 64 KB
  short* sHi = (short*)lds;
  short* sLo = sHi + 16384;
  const int tid = threadIdx.x;
  const int lane = tid & 63, wid = tid >> 6;
  const int l15 = lane & 15, l4 = lane >> 4;
  const int wr = wid >> 2, wc = wid & 3;
  const int row0 = blockIdx.x * HD;
  const unsigned short* e8 = (const unsigned short*)elwf8;

  // ---- gather phase: wave wid owns rows wid*16 .. wid*16+15; f32 hi/lo into LDS ----
  {
    float bx = elb[lane*2], by = elb[lane*2+1];
    for (int n=0; n<16; n++){
      int r = wid*16 + n;
      int node = row0 + r;
      float sx = 0.f, sy = 0.f;
      if (node < N_NODES){
        float2 g = gather_node(node, lane, cnt, eslot, e8, ovf);
        sx = g.x + bx; sy = g.y + by;
      }
      uint hx = bf16rne(sx), hy = bf16rne(sy);
      uint lx = bf16rne(sx - __uint_as_float(hx<<16));
      uint ly = bf16rne(sy - __uint_as_float(hy<<16));
      int sa = r*128 + (((lane>>2) ^ (r & 15)) << 3) + 2*(lane & 3);
      *(uint32_t*)&sHi[sa] = hx | (hy<<16);
      *(uint32_t*)&sLo[sa] = lx | (ly<<16);
    }
  }
  __syncthreads();

  // ---- phase 1: (acc+elb) @ (I+cat1), hi+lo ----
  f32x4 acc[4][2];
  #pragma unroll
  for (int rt=0;rt<4;rt++)
    #pragma unroll
    for (int ct=0;ct<2;ct++) acc[rt][ct] = (f32x4){0.f,0.f,0.f,0.f};
  #pragma unroll
  for (int kt=0;kt<4;kt++){
    int aslot = ((kt*4 + l4) ^ l15) << 3;
    bf16x8 b0 = ((const bf16x8*)B1pk)[((wc*2+0)*4 + kt)*64 + lane];
    bf16x8 b1 = ((const bf16x8*)B1pk)[((wc*2+1)*4 + kt)*64 + lane];
    #pragma unroll
    for (int rt=0;rt<4;rt++){
      int abase = (wr*64 + rt*16 + l15)*128 + aslot;
      bf16x8 ah = *(const bf16x8*)&sHi[abase];
      bf16x8 al = *(const bf16x8*)&sLo[abase];
      acc[rt][0] = __builtin_amdgcn_mfma_f32_16x16x32_bf16(ah, b0, acc[rt][0], 0,0,0);
      acc[rt][1] = __builtin_amdgcn_mfma_f32_16x16x32_bf16(ah, b1, acc[rt][1], 0,0,0);
      acc[rt][0] = __builtin_amdgcn_mfma_f32_16x16x32_bf16(al, b0, acc[rt][0], 0,0,0);
      acc[rt][1] = __builtin_amdgcn_mfma_f32_16x16x32_bf16(al, b1, acc[rt][1], 0,0,0);
    }
  }
  __syncthreads();

  // ---- stage x (f32 -> hi/lo) ----
  #pragma unroll
  for (int p=0;p<8;p++){
    int idx = tid + p*512;
    int r = idx >> 5, half = idx & 31;
    int slot = half >> 1, h4 = (half & 1) * 4;
    float4 v = make_float4(0.f,0.f,0.f,0.f);
    if (row0 + r < N_NODES) v = ((const float4*)x)[(size_t)(row0+r)*32 + half];
    uint hx = bf16rne(v.x), hy = bf16rne(v.y), hz = bf16rne(v.z), hw = bf16rne(v.w);
    uint lx = bf16rne(v.x - __uint_as_float(hx<<16));
    uint ly = bf16rne(v.y - __uint_as_float(hy<<16));
    uint lz = bf16rne(v.z - __uint_as_float(hz<<16));
    uint lw = bf16rne(v.w - __uint_as_float(hw<<16));
    int base = r*128 + ((slot ^ (r & 15)) << 3) + h4;
    *(uint2*)&sHi[base] = make_uint2(hx | (hy<<16), hz | (hw<<16));
    *(uint2*)&sLo[base] = make_uint2(lx | (ly<<16), lz | (lw<<16));
  }
  __syncthreads();

  // ---- phase 2: + x @ M2 (hi+lo) ----
  #pragma unroll
  for (int kt=0;kt<4;kt++){
    int aslot = ((kt*4 + l4) ^ l15) << 3;
    bf16x8 b0 = ((const bf16x8*)B2pk)[((wc*2+0)*4 + kt)*64 + lane];
    bf16x8 b1 = ((const bf16x8*)B2pk)[((wc*2+1)*4 + kt)*64 + lane];
    #pragma unroll
    for (int rt=0;rt<4;rt++){
      int abase = (wr*64 + rt*16 + l15)*128 + aslot;
      bf16x8 ah = *(const bf16x8*)&sHi[abase];
      bf16x8 al = *(const bf16x8*)&sLo[abase];
      acc[rt][0] = __builtin_amdgcn_mfma_f32_16x16x32_bf16(ah, b0, acc[rt][0], 0,0,0);
      acc[rt][1] = __builtin_amdgcn_mfma_f32_16x16x32_bf16(ah, b1, acc[rt][1], 0,0,0);
      acc[rt][0] = __builtin_amdgcn_mfma_f32_16x16x32_bf16(al, b0, acc[rt][0], 0,0,0);
      acc[rt][1] = __builtin_amdgcn_mfma_f32_16x16x32_bf16(al, b1, acc[rt][1], 0,0,0);
    }
  }
  __syncthreads();

  // ---- epilogue p2: +biasv, lrelu, write out2 hi/lo ----
  #pragma unroll
  for (int ct=0;ct<2;ct++){
    int col = wc*32 + ct*16 + l15;
    float bb = biasv[col];
    int slotE = (col >> 3), elem = col & 7;
    #pragma unroll
    for (int rt=0;rt<4;rt++)
      #pragma unroll
      for (int rg=0;rg<4;rg++){
        int r = wr*64 + rt*16 + l4*4 + rg;
        float v = lrelu(acc[rt][ct][rg] + bb);
        uint h = bf16rne(v);
        uint l = bf16rne(v - __uint_as_float(h<<16));
        int sa = r*128 + ((slotE ^ (r & 15)) << 3) + elem;
        sHi[sa] = (short)h; sLo[sa] = (short)l;
      }
  }
  __syncthreads();

  // ---- phase 3: out2 @ W0T (hi+lo) ----
  #pragma unroll
  for (int rt=0;rt<4;rt++)
    #pragma unroll
    for (int ct=0;ct<2;ct++) acc[rt][ct] = (f32x4){0.f,0.f,0.f,0.f};
  #pragma unroll
  for (int kt=0;kt<4;kt++){
    int aslot = ((kt*4 + l4) ^ l15) << 3;
    bf16x8 b0 = ((const bf16x8*)B3pk)[((wc*2+0)*4 + kt)*64 + lane];
    bf16x8 b1 = ((const bf16x8*)B3pk)[((wc*2+1)*4 + kt)*64 + lane];
    #pragma unroll
    for (int rt=0;rt<4;rt++){
      int abase = (wr*64 + rt*16 + l15)*128 + aslot;
      bf16x8 ah = *(const bf16x8*)&sHi[abase];
      bf16x8 al = *(const bf16x8*)&sLo[abase];
      acc[rt][0] = __builtin_amdgcn_mfma_f32_16x16x32_bf16(ah, b0, acc[rt][0], 0,0,0);
      acc[rt][1] = __builtin_amdgcn_mfma_f32_16x16x32_bf16(ah, b1, acc[rt][1], 0,0,0);
      acc[rt][0] = __builtin_amdgcn_mfma_f32_16x16x32_bf16(al, b0, acc[rt][0], 0,0,0);
      acc[rt][1] = __builtin_amdgcn_mfma_f32_16x16x32_bf16(al, b1, acc[rt][1], 0,0,0);
    }
  }
  __syncthreads();

  // ---- epilogue p3: +sb0, lrelu, write h hi/lo ----
  #pragma unroll
  for (int ct=0;ct<2;ct++){
    int col = wc*32 + ct*16 + l15;
    float bb = sb0[col];
    int slotE = (col >> 3), elem = col & 7;
    #pragma unroll
    for (int rt=0;rt<4;rt++)
      #pragma unroll
      for (int rg=0;rg<4;rg++){
        int r = wr*64 + rt*16 + l4*4 + rg;
        float v = lrelu(acc[rt][ct][rg] + bb);
        uint h = bf16rne(v);
        uint l = bf16rne(v - __uint_as_float(h<<16));
        int sa = r*128 + ((slotE ^ (r & 15)) << 3) + elem;
        sHi[sa] = (short)h; sLo[sa] = (short)l;
      }
  }
  __syncthreads();

  // ---- phase 4: h @ W1T (64 cols) ----
  f32x4 y[4];
  #pragma unroll
  for (int ct=0;ct<4;ct++) y[ct] = (f32x4){0.f,0.f,0.f,0.f};
  #pragma unroll
  for (int kt=0;kt<4;kt++){
    int abase = (wid*16 + l15)*128 + (((kt*4 + l4) ^ l15) << 3);
    bf16x8 ah = *(const bf16x8*)&sHi[abase];
    bf16x8 al = *(const bf16x8*)&sLo[abase];
    #pragma unroll
    for (int ct=0;ct<4;ct++){
      bf16x8 b = ((const bf16x8*)B4pk)[(ct*4 + kt)*64 + lane];
      y[ct] = __builtin_amdgcn_mfma_f32_16x16x32_bf16(ah, b, y[ct], 0,0,0);
      y[ct] = __builtin_amdgcn_mfma_f32_16x16x32_bf16(al, b, y[ct], 0,0,0);
    }
  }
  __syncthreads();

  float* sOut = (float*)lds;
  #pragma unroll
  for (int ct=0;ct<4;ct++){
    int col = ct*16 + l15;
    float bb = sb1[col];
    #pragma unroll
    for (int rg=0;rg<4;rg++){
      int r = wid*16 + l4*4 + rg;
      sOut[r*OUTC + col] = lrelu(y[ct][rg] + bb);
    }
  }
  __syncthreads();
  #pragma unroll
  for (int p=0;p<4;p++){
    int o = tid + p*512;
    int r = o >> 4;
    if (row0 + r < N_NODES)
      ((float4*)outp)[(size_t)(row0+r)*16 + (o & 15)] = ((const float4*)sOut)[o];
  }
}

extern "C" void kernel_launch(void* const* d_in, const int* in_sizes, int n_in,
                              void* d_out, int out_size, void* d_ws, size_t ws_size,
                              hipStream_t stream){
  const float* x      = (const float*)d_in[0];
  const int*   ei     = (const int*)d_in[1];
  const float* ew     = (const float*)d_in[2];
  const float* w      = (const float*)d_in[3];
  const float* elw    = (const float*)d_in[4];
  const float* elb    = (const float*)d_in[5];
  const float* node_w = (const float*)d_in[6];
  const float* node_b = (const float*)d_in[7];
  const float* cat1_w = (const float*)d_in[8];
  const float* cat1_b = (const float*)d_in[9];
  const float* cat2_w = (const float*)d_in[10];
  const float* cat2_b = (const float*)d_in[11];
  const float* a0w    = (const float*)d_in[12];
  const float* a0b    = (const float*)d_in[13];
  const float* syn0_w = (const float*)d_in[14];
  const float* syn0_b = (const float*)d_in[15];
  const float* a1w    = (const float*)d_in[16];
  const float* a1b    = (const float*)d_in[17];
  const float* syn1_w = (const float*)d_in[18];
  const float* syn1_b = (const float*)d_in[19];
  float* outp = (float*)d_out;

  uint32_t* wsu = (uint32_t*)d_ws;
  int2*     epair = (int2*)wsu;                            // NBUCK*BCAP int2 (19.2MB)
  uint32_t* elwf8 = wsu + (size_t)NBUCK*BCAP*2;            // N*32 u32 (12.8MB)
  uint32_t* eslot = elwf8 + (size_t)N_NODES*(HD/4);        // N*CAP u32 (12.8MB)
  float* st0    = (float*)(eslot + (size_t)N_NODES*CAP);   // 2560
  float* st1    = st0 + 2560;                              // 1920
  float* M2     = st1 + 1920;                              // 128*128
  float* biasv  = M2 + HD*HD;                              // 128
  float* W0T    = biasv + HD;                              // 128*128
  float* W1T    = W0T + HD*HD;                             // 128*64
  uint32_t* B1pk = (uint32_t*)(W1T + HD*OUTC);             // 8192 u32
  uint32_t* B2pk = B1pk + 8192;
  uint32_t* B3pk = B2pk + 8192;
  uint32_t* B4pk = B3pk + 8192;                            // 4096 u32
  int*   cnt    = (int*)(B4pk + 4096);                     // N+1 (last = ovf count)
  int*   bcur   = cnt + N_NODES + 1;                       // NBUCK
  int4*  ovf    = (int4*)(((uintptr_t)(bcur + NBUCK) + 15) & ~(uintptr_t)15);

  hipMemsetAsync(cnt, 0, (N_NODES+1)*sizeof(int), stream);
  k_binit<<<(NBUCK+255)/256, 256, 0, stream>>>(bcur);
  k_cvt<<<(N_NODES*(HD/4)+255)/256, 256, 0, stream>>>(elw, elwf8);
  k_styles<<<(2560+1920+255)/256, 256, 0, stream>>>(w, a0w, a0b, a1w, a1b, st0, st1);
  k_wmod<<<HD, HD, 0, stream>>>(st0, syn0_w, W0T, HD);
  k_wmod<<<OUTC, HD, 0, stream>>>(st1, syn1_w, W1T, OUTC);
  k_m2bias<<<HD+1, HD, 0, stream>>>(node_w, node_b, cat2_w, cat1_b, cat2_b, M2, biasv);
  k_pack<<<32, 64, 0, stream>>>(cat1_w, HD, HD, 1, B1pk);
  k_pack<<<32, 64, 0, stream>>>(M2,    HD, HD, 0, B2pk);
  k_pack<<<32, 64, 0, stream>>>(W0T,   HD, HD, 0, B3pk);
  k_pack<<<16, 64, 0, stream>>>(W1T,   HD, OUTC, 0, B4pk);
  k_bucketize<<<NCH, 256, 0, stream>>>(ei, ew, bcur, epair, cnt, ovf);
  k_slotfill<<<NBUCK, 256, 0, stream>>>(bcur, epair, cnt, eslot, ovf);
  k_fused<<<(N_NODES+HD-1)/HD, 512, 0, stream>>>(cnt, eslot, elwf8, elb, ovf, x,
                                                 B1pk, B2pk, B3pk, B4pk,
                                                 biasv, syn0_b, syn1_b, outp);
}

// Round 19
// 196.321 us; speedup vs baseline: 1.4482x; 1.4482x over previous
//
#include <hip/hip_runtime.h>
#include <cstdint>
#include <cstddef>

#define N_NODES 100000
#define N_EDGES 1600000
#define HD 128
#define OUTC 64
#define WDIM 512
#define RANKK 10
#define SLOPE 0.01f
#define CAP 32
#define NBUCK ((N_NODES + 255)/256)          // 391 buckets of 256 nodes
#define BCAP 6144                             // entries per bucket region (mean 4096)
#define CHUNK 2048
#define NCH ((N_EDGES + CHUNK - 1)/CHUNK)     // 782

typedef __attribute__((ext_vector_type(8))) short bf16x8;
typedef __attribute__((ext_vector_type(4))) float f32x4;
typedef __attribute__((ext_vector_type(2))) float f32x2;

static __device__ __forceinline__ float lrelu(float v){ return v >= 0.f ? v : SLOPE*v; }
static __device__ __forceinline__ uint32_t bf16rne(float f){
  uint32_t b = __float_as_uint(f);
  return (b + 0x7FFFu + ((b >> 16) & 1u)) >> 16;
}

// ---------------- styles ----------------
__global__ void k_styles(const float* __restrict__ w,
                         const float* __restrict__ a0w, const float* __restrict__ a0b,
                         const float* __restrict__ a1w, const float* __restrict__ a1b,
                         float* __restrict__ st0, float* __restrict__ st1){
  int j = blockIdx.x*blockDim.x + threadIdx.x;
  if (j < 2560){
    float s = a0b[j];
    for (int k=0;k<WDIM;k++) s += w[k]*a0w[k*2560 + j];
    st0[j] = s;
  } else if (j < 2560+1920){
    int jj = j - 2560;
    float s = a1b[jj];
    for (int k=0;k<WDIM;k++) s += w[WDIM + k]*a1w[k*1920 + jj];
    st1[jj] = s;
  }
}

// ---------------- modulated + row-normalized weight, stored TRANSPOSED: wt[k][n] ----
__global__ void k_wmod(const float* __restrict__ st, const float* __restrict__ wgt,
                       float* __restrict__ wt, int c_out){
  int o = blockIdx.x, i = threadIdx.x;
  float mod = 0.f;
  #pragma unroll
  for (int r=0;r<RANKK;r++) mod += st[o*RANKK + r] * st[c_out*RANKK + r*HD + i];
  mod *= 0.31622776601683794f;
  float wv = wgt[o*HD + i] * (mod + 1.f);
  float sq = wv*wv;
  #pragma unroll
  for (int d=1; d<64; d<<=1) sq += __shfl_xor(sq, d, 64);
  __shared__ float red[2];
  if ((i & 63) == 0) red[i>>6] = sq;
  __syncthreads();
  float norm = sqrtf(red[0] + red[1]) + 1e-8f;
  wt[i*c_out + o] = wv / norm;
}

// ---------------- M2 = node_w @ (I + cat2) ; biasv = cat1_b + cat2_b + node_b@(I+cat2)
__global__ void k_m2bias(const float* __restrict__ node_w, const float* __restrict__ node_b,
                         const float* __restrict__ cat2_w, const float* __restrict__ cat1_b,
                         const float* __restrict__ cat2_b,
                         float* __restrict__ M2, float* __restrict__ biasv){
  int i = threadIdx.x;
  int k = blockIdx.x;
  if (k < HD){
    float s = node_w[k*HD + i];
    for (int j=0;j<HD;j++) s += node_w[k*HD + j]*cat2_w[j*HD + i];
    M2[k*HD + i] = s;
  } else {
    float s = cat1_b[i] + cat2_b[i] + node_b[i];
    for (int j=0;j<HD;j++) s += node_b[j]*cat2_w[j*HD + i];
    biasv[i] = s;
  }
}

// ---------------- pack B [K][Ncols] f32 -> bf16 MFMA fragments ----------------
__global__ void k_pack(const float* __restrict__ src, int K, int Ncols, int addI,
                       uint32_t* __restrict__ dst){
  int KTn = K >> 5;
  int kt = blockIdx.x % KTn, nt = blockIdx.x / KTn;
  int lane = threadIdx.x;
  int col = nt*16 + (lane & 15);
  uint32_t o[4];
  #pragma unroll
  for (int jj=0;jj<4;jj++){
    int k0 = kt*32 + (lane>>4)*8 + 2*jj;
    float v0 = src[(size_t)k0*Ncols + col]     + ((addI && k0   == col) ? 1.f : 0.f);
    float v1 = src[(size_t)(k0+1)*Ncols + col] + ((addI && k0+1 == col) ? 1.f : 0.f);
    o[jj] = bf16rne(v0) | (bf16rne(v1) << 16);
  }
  ((uint4*)dst)[blockIdx.x*64 + lane] = make_uint4(o[0], o[1], o[2], o[3]);
}

// ---------------- elw f32 -> fp8 e4m3 packed (4 per u32) ----------------
__global__ void k_cvt(const float* __restrict__ elw, uint32_t* __restrict__ elwf8){
  int i = blockIdx.x*blockDim.x + threadIdx.x;
  if (i < N_NODES*(HD/4)){
    float4 v = ((const float4*)elw)[i];
    int r = 0;
    r = __builtin_amdgcn_cvt_pk_fp8_f32(v.x, v.y, r, false);
    r = __builtin_amdgcn_cvt_pk_fp8_f32(v.z, v.w, r, true);
    elwf8[i] = (uint32_t)r;
  }
}

// ---------------- bcur init ----------------
__global__ void k_binit(int* __restrict__ bcur){
  int b = blockIdx.x*blockDim.x + threadIdx.x;
  if (b < NBUCK) bcur[b] = b*BCAP;
}

// ---------------- P1: chunk -> LDS counting sort by bucket -> grouped flush ----------
__global__ __launch_bounds__(256) void k_bucketize(const int* __restrict__ ei,
                                                   const float* __restrict__ ew,
                                                   int* __restrict__ bcur,
                                                   int2* __restrict__ epair,
                                                   int* __restrict__ cnt,
                                                   int4* __restrict__ ovf){
  __shared__ int2 ed[CHUNK];
  __shared__ unsigned short bkt[CHUNK];
  __shared__ unsigned short sidx[CHUNK];
  __shared__ int sa[512], sb[512];
  __shared__ int off[NBUCK], pcur[NBUCK], gbase[NBUCK];
  const int tid = threadIdx.x;
  const int e0 = blockIdx.x * CHUNK;
  const int ne = min(CHUNK, N_EDGES - e0);

  sa[tid] = 0; sa[tid+256] = 0;
  __syncthreads();
  for (int i=tid; i<ne; i+=256){
    int src = ei[e0+i], dst = ei[N_EDGES+e0+i];
    ed[i]  = make_int2(src | ((dst & 255) << 17), __float_as_int(ew[e0+i]));
    int b = dst >> 8;
    bkt[i] = (unsigned short)b;
    atomicAdd(&sa[b], 1);
  }
  __syncthreads();
  int c0 = sa[tid], c1 = sa[tid+256];
  int* cur = sa; int* oth = sb;
  for (int d=1; d<512; d<<=1){
    int v0 = cur[tid]     + (tid     >= d ? cur[tid-d]     : 0);
    int v1 = cur[tid+256] + (tid+256 >= d ? cur[tid+256-d] : 0);
    oth[tid] = v0; oth[tid+256] = v1;
    __syncthreads();
    int* t_ = cur; cur = oth; oth = t_;
  }
  off[tid] = cur[tid] - c0;  pcur[tid] = cur[tid] - c0;
  if (tid+256 < NBUCK){ off[tid+256] = cur[tid+256] - c1; pcur[tid+256] = cur[tid+256] - c1; }
  __syncthreads();
  int rot = (blockIdx.x * 73) % NBUCK;
  for (int k=tid; k<NBUCK; k+=256){
    int b = k + rot; if (b >= NBUCK) b -= NBUCK;
    int cb = cur[b] - off[b];
    if (cb > 0) gbase[b] = atomicAdd(&bcur[b], cb);
  }
  __syncthreads();
  for (int i=tid; i<ne; i+=256){
    int s = atomicAdd(&pcur[bkt[i]], 1);
    sidx[s] = (unsigned short)i;
  }
  __syncthreads();
  for (int j=tid; j<ne; j+=256){
    int i = sidx[j];
    int b = bkt[i];
    int addr = gbase[b] + (j - off[b]);
    if (addr < (b+1)*BCAP){
      epair[addr] = ed[i];
    } else {
      int oi = atomicAdd(&cnt[N_NODES], 1);
      ovf[oi] = make_int4(ed[i].x & 0x1FFFF, b*256 + ((ed[i].x>>17)&255), ed[i].y, 0);
    }
  }
}

// ---------------- P2: bucket region -> per-node slots ----------------
__global__ __launch_bounds__(256) void k_slotfill(const int* __restrict__ bcur,
                                                  const int2* __restrict__ epair,
                                                  int* __restrict__ cnt,
                                                  uint32_t* __restrict__ eslot,
                                                  int4* __restrict__ ovf){
  __shared__ int lcnt[256];
  const int tid = threadIdx.x;
  const int b = blockIdx.x;
  const int n0 = b*256;
  const int2* reg = epair + (size_t)b*BCAP;
  const int count = min(bcur[b], (b+1)*BCAP) - b*BCAP;
  lcnt[tid] = 0;
  __syncthreads();
  for (int j=tid; j<count; j+=256){
    int2 rec = reg[j];
    int ldst = (rec.x >> 17) & 255;
    int pos = atomicAdd(&lcnt[ldst], 1);
    if (pos < CAP){
      uint32_t wb = (uint32_t)rec.y;
      uint32_t wenc = ((wb + 0x8000u) >> 16) & 0x7FFFu;
      eslot[(size_t)(n0+ldst)*CAP + pos] = (uint32_t)(rec.x & 0x1FFFF) | (wenc << 17);
    } else {
      int oi = atomicAdd(&cnt[N_NODES], 1);
      ovf[oi] = make_int4(rec.x & 0x1FFFF, n0 + ldst, rec.y, 0);
    }
  }
  __syncthreads();
  if (n0 + tid < N_NODES) cnt[n0 + tid] = lcnt[tid];
}

// ---------------- gather: TWO nodes per wave (half-wave each), fp8 rows ----------
// lanes 0-31 = node A (u32/lane = 4 elems), lanes 32-63 = node B. Row-load instrs
// halve per node-edge; loop bound = max(degA,degB). Fully masked 8-batches keep 8
// loads in flight. 50K waves of TLP.
__global__ __launch_bounds__(256) void k_gather(const int* __restrict__ cnt,
                         const uint32_t* __restrict__ eslot,
                         const uint32_t* __restrict__ elwf8, const float* __restrict__ elb,
                         const int4* __restrict__ ovf,
                         uint32_t* __restrict__ accbb){
  int wv = (blockIdx.x * blockDim.x + threadIdx.x) >> 6;
  int lane = threadIdx.x & 63;
  if (wv >= N_NODES/2) return;               // N even: 2*wv+1 < N always
  const int half = lane >> 5, l32 = lane & 31;
  const int node = wv*2 + half;
  const uint32_t* base = eslot + (size_t)node*CAP;
  int c = cnt[node];
  int cc = min(c, CAP);
  int mx = max(cc, __shfl_xor(cc, 32, 64));
  int last = max(cc - 1, 0);
  float s0=0.f, s1=0.f, s2=0.f, s3=0.f;
  for (int e=0; e<mx; e+=8){
    int i0 = min(e+0,last), i1 = min(e+1,last), i2 = min(e+2,last), i3 = min(e+3,last);
    int i4 = min(e+4,last), i5 = min(e+5,last), i6 = min(e+6,last), i7 = min(e+7,last);
    uint32_t p0 = base[i0], p1 = base[i1], p2 = base[i2], p3 = base[i3];
    uint32_t p4 = base[i4], p5 = base[i5], p6 = base[i6], p7 = base[i7];
    uint32_t u0 = elwf8[(p0 & 0x1FFFFu)*32u + l32];
    uint32_t u1 = elwf8[(p1 & 0x1FFFFu)*32u + l32];
    uint32_t u2 = elwf8[(p2 & 0x1FFFFu)*32u + l32];
    uint32_t u3 = elwf8[(p3 & 0x1FFFFu)*32u + l32];
    uint32_t u4 = elwf8[(p4 & 0x1FFFFu)*32u + l32];
    uint32_t u5 = elwf8[(p5 & 0x1FFFFu)*32u + l32];
    uint32_t u6 = elwf8[(p6 & 0x1FFFFu)*32u + l32];
    uint32_t u7 = elwf8[(p7 & 0x1FFFFu)*32u + l32];
    float w0 = (e+0 < cc) ? __uint_as_float((p0 >> 17) << 16) : 0.f;
    float w1 = (e+1 < cc) ? __uint_as_float((p1 >> 17) << 16) : 0.f;
    float w2 = (e+2 < cc) ? __uint_as_float((p2 >> 17) << 16) : 0.f;
    float w3 = (e+3 < cc) ? __uint_as_float((p3 >> 17) << 16) : 0.f;
    float w4 = (e+4 < cc) ? __uint_as_float((p4 >> 17) << 16) : 0.f;
    float w5 = (e+5 < cc) ? __uint_as_float((p5 >> 17) << 16) : 0.f;
    float w6 = (e+6 < cc) ? __uint_as_float((p6 >> 17) << 16) : 0.f;
    float w7 = (e+7 < cc) ? __uint_as_float((p7 >> 17) << 16) : 0.f;
    f32x2 a0 = __builtin_amdgcn_cvt_pk_f32_fp8((int)u0, false);
    f32x2 b0 = __builtin_amdgcn_cvt_pk_f32_fp8((int)u0, true);
    f32x2 a1 = __builtin_amdgcn_cvt_pk_f32_fp8((int)u1, false);
    f32x2 b1 = __builtin_amdgcn_cvt_pk_f32_fp8((int)u1, true);
    f32x2 a2 = __builtin_amdgcn_cvt_pk_f32_fp8((int)u2, false);
    f32x2 b2 = __builtin_amdgcn_cvt_pk_f32_fp8((int)u2, true);
    f32x2 a3 = __builtin_amdgcn_cvt_pk_f32_fp8((int)u3, false);
    f32x2 b3 = __builtin_amdgcn_cvt_pk_f32_fp8((int)u3, true);
    f32x2 a4 = __builtin_amdgcn_cvt_pk_f32_fp8((int)u4, false);
    f32x2 b4 = __builtin_amdgcn_cvt_pk_f32_fp8((int)u4, true);
    f32x2 a5 = __builtin_amdgcn_cvt_pk_f32_fp8((int)u5, false);
    f32x2 b5 = __builtin_amdgcn_cvt_pk_f32_fp8((int)u5, true);
    f32x2 a6 = __builtin_amdgcn_cvt_pk_f32_fp8((int)u6, false);
    f32x2 b6 = __builtin_amdgcn_cvt_pk_f32_fp8((int)u6, true);
    f32x2 a7 = __builtin_amdgcn_cvt_pk_f32_fp8((int)u7, false);
    f32x2 b7 = __builtin_amdgcn_cvt_pk_f32_fp8((int)u7, true);
    s0 += a0.x*w0; s1 += a0.y*w0; s2 += b0.x*w0; s3 += b0.y*w0;
    s0 += a1.x*w1; s1 += a1.y*w1; s2 += b1.x*w1; s3 += b1.y*w1;
    s0 += a2.x*w2; s1 += a2.y*w2; s2 += b2.x*w2; s3 += b2.y*w2;
    s0 += a3.x*w3; s1 += a3.y*w3; s2 += b3.x*w3; s3 += b3.y*w3;
    s0 += a4.x*w4; s1 += a4.y*w4; s2 += b4.x*w4; s3 += b4.y*w4;
    s0 += a5.x*w5; s1 += a5.y*w5; s2 += b5.x*w5; s3 += b5.y*w5;
    s0 += a6.x*w6; s1 += a6.y*w6; s2 += b6.x*w6; s3 += b6.y*w6;
    s0 += a7.x*w7; s1 += a7.y*w7; s2 += b7.x*w7; s3 += b7.y*w7;
  }
  {
    int ocnt = cnt[N_NODES];
    for (int i = 0; i < ocnt; ++i){
      int4 o = ovf[i];
      if (o.y == node){
        float wvv = __int_as_float(o.z);
        uint32_t u = elwf8[(uint32_t)o.x*32u + l32];
        f32x2 fa = __builtin_amdgcn_cvt_pk_f32_fp8((int)u, false);
        f32x2 fb = __builtin_amdgcn_cvt_pk_f32_fp8((int)u, true);
        s0 += fa.x*wvv; s1 += fa.y*wvv; s2 += fb.x*wvv; s3 += fb.y*wvv;
      }
    }
  }
  float4 bb = ((const float4*)elb)[l32];
  s0 += bb.x; s1 += bb.y; s2 += bb.z; s3 += bb.w;
  uint32_t oa = bf16rne(s0) | (bf16rne(s1) << 16);
  uint32_t ob = bf16rne(s2) | (bf16rne(s3) << 16);
  *(uint2*)&accbb[(size_t)node*(HD/2) + 2*l32] = make_uint2(oa, ob);
}

// ---------------- fused node chain via bf16 MFMA, hi/lo compensated A ----------------
__global__ __launch_bounds__(512, 4) void k_fused(
    const uint32_t* __restrict__ accbb, const float* __restrict__ x,
    const uint32_t* __restrict__ B1pk, const uint32_t* __restrict__ B2pk,
    const uint32_t* __restrict__ B3pk, const uint32_t* __restrict__ B4pk,
    const float* __restrict__ biasv, const float* __restrict__ sb0,
    const float* __restrict__ sb1, float* __restrict__ outp){
  __shared__ uint32_t lds[16384];                 // 64 KB
  short* sHi = (short*)lds;
  short* sLo = sHi + 16384;
  const int tid = threadIdx.x;
  const int lane = tid & 63, wid = tid >> 6;
  const int l15 = lane & 15, l4 = lane >> 4;
  const int wr = wid >> 2, wc = wid & 3;
  const int row0 = blockIdx.x * HD;

  #pragma unroll
  for (int p=0;p<4;p++){
    int idx = tid + p*512;
    int r = idx >> 4, slot = idx & 15;
    uint4 v = make_uint4(0,0,0,0);
    if (row0 + r < N_NODES) v = ((const uint4*)accbb)[(size_t)(row0+r)*16 + slot];
    *(uint4*)&sHi[r*128 + ((slot ^ (r & 15)) << 3)] = v;
  }
  __syncthreads();

  f32x4 acc[4][2];
  #pragma unroll
  for (int rt=0;rt<4;rt++)
    #pragma unroll
    for (int ct=0;ct<2;ct++) acc[rt][ct] = (f32x4){0.f,0.f,0.f,0.f};
  #pragma unroll
  for (int kt=0;kt<4;kt++){
    int aslot = ((kt*4 + l4) ^ l15) << 3;
    bf16x8 b0 = ((const bf16x8*)B1pk)[((wc*2+0)*4 + kt)*64 + lane];
    bf16x8 b1 = ((const bf16x8*)B1pk)[((wc*2+1)*4 + kt)*64 + lane];
    #pragma unroll
    for (int rt=0;rt<4;rt++){
      bf16x8 a = *(const bf16x8*)&sHi[(wr*64 + rt*16 + l15)*128 + aslot];
      acc[rt][0] = __builtin_amdgcn_mfma_f32_16x16x32_bf16(a, b0, acc[rt][0], 0,0,0);
      acc[rt][1] = __builtin_amdgcn_mfma_f32_16x16x32_bf16(a, b1, acc[rt][1], 0,0,0);
    }
  }
  __syncthreads();

  #pragma unroll
  for (int p=0;p<8;p++){
    int idx = tid + p*512;
    int r = idx >> 5, half = idx & 31;
    int slot = half >> 1, h4 = (half & 1) * 4;
    float4 v = make_float4(0.f,0.f,0.f,0.f);
    if (row0 + r < N_NODES) v = ((const float4*)x)[(size_t)(row0+r)*32 + half];
    uint hx = bf16rne(v.x), hy = bf16rne(v.y), hz = bf16rne(v.z), hw = bf16rne(v.w);
    uint lx = bf16rne(v.x - __uint_as_float(hx<<16));
    uint ly = bf16rne(v.y - __uint_as_float(hy<<16));
    uint lz = bf16rne(v.z - __uint_as_float(hz<<16));
    uint lw = bf16rne(v.w - __uint_as_float(hw<<16));
    int base = r*128 + ((slot ^ (r & 15)) << 3) + h4;
    *(uint2*)&sHi[base] = make_uint2(hx | (hy<<16), hz | (hw<<16));
    *(uint2*)&sLo[base] = make_uint2(lx | (ly<<16), lz | (lw<<16));
  }
  __syncthreads();

  #pragma unroll
  for (int kt=0;kt<4;kt++){
    int aslot = ((kt*4 + l4) ^ l15) << 3;
    bf16x8 b0 = ((const bf16x8*)B2pk)[((wc*2+0)*4 + kt)*64 + lane];
    bf16x8 b1 = ((const bf16x8*)B2pk)[((wc*2+1)*4 + kt)*64 + lane];
    #pragma unroll
    for (int rt=0;rt<4;rt++){
      int abase = (wr*64 + rt*16 + l15)*128 + aslot;
      bf16x8 ah = *(const bf16x8*)&sHi[abase];
      bf16x8 al = *(const bf16x8*)&sLo[abase];
      acc[rt][0] = __builtin_amdgcn_mfma_f32_16x16x32_bf16(ah, b0, acc[rt][0], 0,0,0);
      acc[rt][1] = __builtin_amdgcn_mfma_f32_16x16x32_bf16(ah, b1, acc[rt][1], 0,0,0);
      acc[rt][0] = __builtin_amdgcn_mfma_f32_16x16x32_bf16(al, b0, acc[rt][0], 0,0,0);
      acc[rt][1] = __builtin_amdgcn_mfma_f32_16x16x32_bf16(al, b1, acc[rt][1], 0,0,0);
    }
  }
  __syncthreads();

  #pragma unroll
  for (int ct=0;ct<2;ct++){
    int col = wc*32 + ct*16 + l15;
    float bb = biasv[col];
    int slotE = (col >> 3), elem = col & 7;
    #pragma unroll
    for (int rt=0;rt<4;rt++)
      #pragma unroll
      for (int rg=0;rg<4;rg++){
        int r = wr*64 + rt*16 + l4*4 + rg;
        float v = lrelu(acc[rt][ct][rg] + bb);
        uint h = bf16rne(v);
        uint l = bf16rne(v - __uint_as_float(h<<16));
        int sa = r*128 + ((slotE ^ (r & 15)) << 3) + elem;
        sHi[sa] = (short)h; sLo[sa] = (short)l;
      }
  }
  __syncthreads();

  #pragma unroll
  for (int rt=0;rt<4;rt++)
    #pragma unroll
    for (int ct=0;ct<2;ct++) acc[rt][ct] = (f32x4){0.f,0.f,0.f,0.f};
  #pragma unroll
  for (int kt=0;kt<4;kt++){
    int aslot = ((kt*4 + l4) ^ l15) << 3;
    bf16x8 b0 = ((const bf16x8*)B3pk)[((wc*2+0)*4 + kt)*64 + lane];
    bf16x8 b1 = ((const bf16x8*)B3pk)[((wc*2+1)*4 + kt)*64 + lane];
    #pragma unroll
    for (int rt=0;rt<4;rt++){
      int abase = (wr*64 + rt*16 + l15)*128 + aslot;
      bf16x8 ah = *(const bf16x8*)&sHi[abase];
      bf16x8 al = *(const bf16x8*)&sLo[abase];
      acc[rt][0] = __builtin_amdgcn_mfma_f32_16x16x32_bf16(ah, b0, acc[rt][0], 0,0,0);
      acc[rt][1] = __builtin_amdgcn_mfma_f32_16x16x32_bf16(ah, b1, acc[rt][1], 0,0,0);
      acc[rt][0] = __builtin_amdgcn_mfma_f32_16x16x32_bf16(al, b0, acc[rt][0], 0,0,0);
      acc[rt][1] = __builtin_amdgcn_mfma_f32_16x16x32_bf16(al, b1, acc[rt][1], 0,0,0);
    }
  }
  __syncthreads();

  #pragma unroll
  for (int ct=0;ct<2;ct++){
    int col = wc*32 + ct*16 + l15;
    float bb = sb0[col];
    int slotE = (col >> 3), elem = col & 7;
    #pragma unroll
    for (int rt=0;rt<4;rt++)
      #pragma unroll
      for (int rg=0;rg<4;rg++){
        int r = wr*64 + rt*16 + l4*4 + rg;
        float v = lrelu(acc[rt][ct][rg] + bb);
        uint h = bf16rne(v);
        uint l = bf16rne(v - __uint_as_float(h<<16));
        int sa = r*128 + ((slotE ^ (r & 15)) << 3) + elem;
        sHi[sa] = (short)h; sLo[sa] = (short)l;
      }
  }
  __syncthreads();

  f32x4 y[4];
  #pragma unroll
  for (int ct=0;ct<4;ct++) y[ct] = (f32x4){0.f,0.f,0.f,0.f};
  #pragma unroll
  for (int kt=0;kt<4;kt++){
    int abase = (wid*16 + l15)*128 + (((kt*4 + l4) ^ l15) << 3);
    bf16x8 ah = *(const bf16x8*)&sHi[abase];
    bf16x8 al = *(const bf16x8*)&sLo[abase];
    #pragma unroll
    for (int ct=0;ct<4;ct++){
      bf16x8 b = ((const bf16x8*)B4pk)[(ct*4 + kt)*64 + lane];
      y[ct] = __builtin_amdgcn_mfma_f32_16x16x32_bf16(ah, b, y[ct], 0,0,0);
      y[ct] = __builtin_amdgcn_mfma_f32_16x16x32_bf16(al, b, y[ct], 0,0,0);
    }
  }
  __syncthreads();

  float* sOut = (float*)lds;
  #pragma unroll
  for (int ct=0;ct<4;ct++){
    int col = ct*16 + l15;
    float bb = sb1[col];
    #pragma unroll
    for (int rg=0;rg<4;rg++){
      int r = wid*16 + l4*4 + rg;
      sOut[r*OUTC + col] = lrelu(y[ct][rg] + bb);
    }
  }
  __syncthreads();
  #pragma unroll
  for (int p=0;p<4;p++){
    int o = tid + p*512;
    int r = o >> 4;
    if (row0 + r < N_NODES)
      ((float4*)outp)[(size_t)(row0+r)*16 + (o & 15)] = ((const float4*)sOut)[o];
  }
}

extern "C" void kernel_launch(void* const* d_in, const int* in_sizes, int n_in,
                              void* d_out, int out_size, void* d_ws, size_t ws_size,
                              hipStream_t stream){
  const float* x      = (const float*)d_in[0];
  const int*   ei     = (const int*)d_in[1];
  const float* ew     = (const float*)d_in[2];
  const float* w      = (const float*)d_in[3];
  const float* elw    = (const float*)d_in[4];
  const float* elb    = (const float*)d_in[5];
  const float* node_w = (const float*)d_in[6];
  const float* node_b = (const float*)d_in[7];
  const float* cat1_w = (const float*)d_in[8];
  const float* cat1_b = (const float*)d_in[9];
  const float* cat2_w = (const float*)d_in[10];
  const float* cat2_b = (const float*)d_in[11];
  const float* a0w    = (const float*)d_in[12];
  const float* a0b    = (const float*)d_in[13];
  const float* syn0_w = (const float*)d_in[14];
  const float* syn0_b = (const float*)d_in[15];
  const float* a1w    = (const float*)d_in[16];
  const float* a1b    = (const float*)d_in[17];
  const float* syn1_w = (const float*)d_in[18];
  const float* syn1_b = (const float*)d_in[19];
  float* outp = (float*)d_out;

  uint32_t* wsu = (uint32_t*)d_ws;
  uint32_t* accbb = wsu;                                   // N*64 u32 (25.6MB)
  int2*     epair = (int2*)accbb;                          // ALIAS (19.2MB), dead before gather
  uint32_t* elwf8 = accbb + (size_t)N_NODES*(HD/2);        // N*32 u32 (12.8MB)
  uint32_t* eslot = elwf8 + (size_t)N_NODES*(HD/4);        // N*CAP u32 (12.8MB)
  float* st0    = (float*)(eslot + (size_t)N_NODES*CAP);   // 2560
  float* st1    = st0 + 2560;                              // 1920
  float* M2     = st1 + 1920;                              // 128*128
  float* biasv  = M2 + HD*HD;                              // 128
  float* W0T    = biasv + HD;                              // 128*128
  float* W1T    = W0T + HD*HD;                             // 128*64
  uint32_t* B1pk = (uint32_t*)(W1T + HD*OUTC);             // 8192 u32
  uint32_t* B2pk = B1pk + 8192;
  uint32_t* B3pk = B2pk + 8192;
  uint32_t* B4pk = B3pk + 8192;                            // 4096 u32
  int*   cnt    = (int*)(B4pk + 4096);                     // N+1 (last = ovf count)
  int*   bcur   = cnt + N_NODES + 1;                       // NBUCK
  int4*  ovf    = (int4*)(((uintptr_t)(bcur + NBUCK) + 15) & ~(uintptr_t)15);

  hipMemsetAsync(cnt, 0, (N_NODES+1)*sizeof(int), stream);
  k_binit<<<(NBUCK+255)/256, 256, 0, stream>>>(bcur);
  k_cvt<<<(N_NODES*(HD/4)+255)/256, 256, 0, stream>>>(elw, elwf8);
  k_styles<<<(2560+1920+255)/256, 256, 0, stream>>>(w, a0w, a0b, a1w, a1b, st0, st1);
  k_wmod<<<HD, HD, 0, stream>>>(st0, syn0_w, W0T, HD);
  k_wmod<<<OUTC, HD, 0, stream>>>(st1, syn1_w, W1T, OUTC);
  k_m2bias<<<HD+1, HD, 0, stream>>>(node_w, node_b, cat2_w, cat1_b, cat2_b, M2, biasv);
  k_pack<<<32, 64, 0, stream>>>(cat1_w, HD, HD, 1, B1pk);
  k_pack<<<32, 64, 0, stream>>>(M2,    HD, HD, 0, B2pk);
  k_pack<<<32, 64, 0, stream>>>(W0T,   HD, HD, 0, B3pk);
  k_pack<<<16, 64, 0, stream>>>(W1T,   HD, OUTC, 0, B4pk);
  k_bucketize<<<NCH, 256, 0, stream>>>(ei, ew, bcur, epair, cnt, ovf);
  k_slotfill<<<NBUCK, 256, 0, stream>>>(bcur, epair, cnt, eslot, ovf);
  k_gather<<<((N_NODES/2)*64+255)/256, 256, 0, stream>>>(cnt, eslot, elwf8, elb, ovf, accbb);
  k_fused<<<(N_NODES+HD-1)/HD, 512, 0, stream>>>(accbb, x, B1pk, B2pk, B3pk, B4pk,
                                                 biasv, syn0_b, syn1_b, outp);
}

// Round 20
// 187.070 us; speedup vs baseline: 1.5198x; 1.0495x over previous
//
#include <hip/hip_runtime.h>
#include <cstdint>
#include <cstddef>

#define N_NODES 100000
#define N_EDGES 1600000
#define HD 128
#define OUTC 64
#define WDIM 512
#define RANKK 10
#define SLOPE 0.01f
#define CAP 32
#define NBUCK ((N_NODES + 255)/256)          // 391 buckets of 256 nodes
#define BCAP 6144                             // entries per bucket region (mean 4096)
#define CHUNK 2048
#define NCH ((N_EDGES + CHUNK - 1)/CHUNK)     // 782

typedef __attribute__((ext_vector_type(8))) short bf16x8;
typedef __attribute__((ext_vector_type(4))) float f32x4;
typedef __attribute__((ext_vector_type(2))) float f32x2;

static __device__ __forceinline__ float lrelu(float v){ return v >= 0.f ? v : SLOPE*v; }
static __device__ __forceinline__ uint32_t bf16rne(float f){
  uint32_t b = __float_as_uint(f);
  return (b + 0x7FFFu + ((b >> 16) & 1u)) >> 16;
}

// ---------------- styles ----------------
__global__ void k_styles(const float* __restrict__ w,
                         const float* __restrict__ a0w, const float* __restrict__ a0b,
                         const float* __restrict__ a1w, const float* __restrict__ a1b,
                         float* __restrict__ st0, float* __restrict__ st1){
  int j = blockIdx.x*blockDim.x + threadIdx.x;
  if (j < 2560){
    float s = a0b[j];
    for (int k=0;k<WDIM;k++) s += w[k]*a0w[k*2560 + j];
    st0[j] = s;
  } else if (j < 2560+1920){
    int jj = j - 2560;
    float s = a1b[jj];
    for (int k=0;k<WDIM;k++) s += w[WDIM + k]*a1w[k*1920 + jj];
    st1[jj] = s;
  }
}

// ---------------- modulated + row-normalized weight, stored TRANSPOSED: wt[k][n] ----
__global__ void k_wmod(const float* __restrict__ st, const float* __restrict__ wgt,
                       float* __restrict__ wt, int c_out){
  int o = blockIdx.x, i = threadIdx.x;
  float mod = 0.f;
  #pragma unroll
  for (int r=0;r<RANKK;r++) mod += st[o*RANKK + r] * st[c_out*RANKK + r*HD + i];
  mod *= 0.31622776601683794f;
  float wv = wgt[o*HD + i] * (mod + 1.f);
  float sq = wv*wv;
  #pragma unroll
  for (int d=1; d<64; d<<=1) sq += __shfl_xor(sq, d, 64);
  __shared__ float red[2];
  if ((i & 63) == 0) red[i>>6] = sq;
  __syncthreads();
  float norm = sqrtf(red[0] + red[1]) + 1e-8f;
  wt[i*c_out + o] = wv / norm;
}

// ---------------- M2 = node_w @ (I + cat2) ; biasv = cat1_b + cat2_b + node_b@(I+cat2)
__global__ void k_m2bias(const float* __restrict__ node_w, const float* __restrict__ node_b,
                         const float* __restrict__ cat2_w, const float* __restrict__ cat1_b,
                         const float* __restrict__ cat2_b,
                         float* __restrict__ M2, float* __restrict__ biasv){
  int i = threadIdx.x;
  int k = blockIdx.x;
  if (k < HD){
    float s = node_w[k*HD + i];
    for (int j=0;j<HD;j++) s += node_w[k*HD + j]*cat2_w[j*HD + i];
    M2[k*HD + i] = s;
  } else {
    float s = cat1_b[i] + cat2_b[i] + node_b[i];
    for (int j=0;j<HD;j++) s += node_b[j]*cat2_w[j*HD + i];
    biasv[i] = s;
  }
}

// ---------------- pack B [K][Ncols] f32 -> bf16 MFMA fragments ----------------
__global__ void k_pack(const float* __restrict__ src, int K, int Ncols, int addI,
                       uint32_t* __restrict__ dst){
  int KTn = K >> 5;
  int kt = blockIdx.x % KTn, nt = blockIdx.x / KTn;
  int lane = threadIdx.x;
  int col = nt*16 + (lane & 15);
  uint32_t o[4];
  #pragma unroll
  for (int jj=0;jj<4;jj++){
    int k0 = kt*32 + (lane>>4)*8 + 2*jj;
    float v0 = src[(size_t)k0*Ncols + col]     + ((addI && k0   == col) ? 1.f : 0.f);
    float v1 = src[(size_t)(k0+1)*Ncols + col] + ((addI && k0+1 == col) ? 1.f : 0.f);
    o[jj] = bf16rne(v0) | (bf16rne(v1) << 16);
  }
  ((uint4*)dst)[blockIdx.x*64 + lane] = make_uint4(o[0], o[1], o[2], o[3]);
}

// ---------------- elw f32 -> fp8 e4m3 packed (4 per u32) ----------------
__global__ void k_cvt(const float* __restrict__ elw, uint32_t* __restrict__ elwf8){
  int i = blockIdx.x*blockDim.x + threadIdx.x;
  if (i < N_NODES*(HD/4)){
    float4 v = ((const float4*)elw)[i];
    int r = 0;
    r = __builtin_amdgcn_cvt_pk_fp8_f32(v.x, v.y, r, false);
    r = __builtin_amdgcn_cvt_pk_fp8_f32(v.z, v.w, r, true);
    elwf8[i] = (uint32_t)r;
  }
}

// ---------------- bcur init ----------------
__global__ void k_binit(int* __restrict__ bcur){
  int b = blockIdx.x*blockDim.x + threadIdx.x;
  if (b < NBUCK) bcur[b] = b*BCAP;
}

// ---------------- P1: chunk -> LDS counting sort by bucket -> grouped flush ----------
__global__ __launch_bounds__(256) void k_bucketize(const int* __restrict__ ei,
                                                   const float* __restrict__ ew,
                                                   int* __restrict__ bcur,
                                                   int2* __restrict__ epair,
                                                   int* __restrict__ cnt,
                                                   int4* __restrict__ ovf){
  __shared__ int2 ed[CHUNK];
  __shared__ unsigned short bkt[CHUNK];
  __shared__ unsigned short sidx[CHUNK];
  __shared__ int sa[512], sb[512];
  __shared__ int off[NBUCK], pcur[NBUCK], gbase[NBUCK];
  const int tid = threadIdx.x;
  const int e0 = blockIdx.x * CHUNK;
  const int ne = min(CHUNK, N_EDGES - e0);

  sa[tid] = 0; sa[tid+256] = 0;
  __syncthreads();
  for (int i=tid; i<ne; i+=256){
    int src = ei[e0+i], dst = ei[N_EDGES+e0+i];
    ed[i]  = make_int2(src | ((dst & 255) << 17), __float_as_int(ew[e0+i]));
    int b = dst >> 8;
    bkt[i] = (unsigned short)b;
    atomicAdd(&sa[b], 1);
  }
  __syncthreads();
  int c0 = sa[tid], c1 = sa[tid+256];
  int* cur = sa; int* oth = sb;
  for (int d=1; d<512; d<<=1){
    int v0 = cur[tid]     + (tid     >= d ? cur[tid-d]     : 0);
    int v1 = cur[tid+256] + (tid+256 >= d ? cur[tid+256-d] : 0);
    oth[tid] = v0; oth[tid+256] = v1;
    __syncthreads();
    int* t_ = cur; cur = oth; oth = t_;
  }
  off[tid] = cur[tid] - c0;  pcur[tid] = cur[tid] - c0;
  if (tid+256 < NBUCK){ off[tid+256] = cur[tid+256] - c1; pcur[tid+256] = cur[tid+256] - c1; }
  __syncthreads();
  int rot = (blockIdx.x * 73) % NBUCK;
  for (int k=tid; k<NBUCK; k+=256){
    int b = k + rot; if (b >= NBUCK) b -= NBUCK;
    int cb = cur[b] - off[b];
    if (cb > 0) gbase[b] = atomicAdd(&bcur[b], cb);
  }
  __syncthreads();
  for (int i=tid; i<ne; i+=256){
    int s = atomicAdd(&pcur[bkt[i]], 1);
    sidx[s] = (unsigned short)i;
  }
  __syncthreads();
  for (int j=tid; j<ne; j+=256){
    int i = sidx[j];
    int b = bkt[i];
    int addr = gbase[b] + (j - off[b]);
    if (addr < (b+1)*BCAP){
      epair[addr] = ed[i];
    } else {
      int oi = atomicAdd(&cnt[N_NODES], 1);
      ovf[oi] = make_int4(ed[i].x & 0x1FFFF, b*256 + ((ed[i].x>>17)&255), ed[i].y, 0);
    }
  }
}

// ---------------- P2: bucket region -> per-node slots ----------------
__global__ __launch_bounds__(256) void k_slotfill(const int* __restrict__ bcur,
                                                  const int2* __restrict__ epair,
                                                  int* __restrict__ cnt,
                                                  uint32_t* __restrict__ eslot,
                                                  int4* __restrict__ ovf){
  __shared__ int lcnt[256];
  const int tid = threadIdx.x;
  const int b = blockIdx.x;
  const int n0 = b*256;
  const int2* reg = epair + (size_t)b*BCAP;
  const int count = min(bcur[b], (b+1)*BCAP) - b*BCAP;
  lcnt[tid] = 0;
  __syncthreads();
  for (int j=tid; j<count; j+=256){
    int2 rec = reg[j];
    int ldst = (rec.x >> 17) & 255;
    int pos = atomicAdd(&lcnt[ldst], 1);
    if (pos < CAP){
      uint32_t wb = (uint32_t)rec.y;
      uint32_t wenc = ((wb + 0x8000u) >> 16) & 0x7FFFu;
      eslot[(size_t)(n0+ldst)*CAP + pos] = (uint32_t)(rec.x & 0x1FFFF) | (wenc << 17);
    } else {
      int oi = atomicAdd(&cnt[N_NODES], 1);
      ovf[oi] = make_int4(rec.x & 0x1FFFF, n0 + ldst, rec.y, 0);
    }
  }
  __syncthreads();
  if (n0 + tid < N_NODES) cnt[n0 + tid] = lcnt[tid];
}

// ---------------- gather: TWO nodes per wave (half-wave each), fp8 rows ----------
__global__ __launch_bounds__(256) void k_gather(const int* __restrict__ cnt,
                         const uint32_t* __restrict__ eslot,
                         const uint32_t* __restrict__ elwf8, const float* __restrict__ elb,
                         const int4* __restrict__ ovf,
                         uint32_t* __restrict__ accbb){
  int wv = (blockIdx.x * blockDim.x + threadIdx.x) >> 6;
  int lane = threadIdx.x & 63;
  if (wv >= N_NODES/2) return;               // N even: 2*wv+1 < N always
  const int half = lane >> 5, l32 = lane & 31;
  const int node = wv*2 + half;
  const uint32_t* base = eslot + (size_t)node*CAP;
  int c = cnt[node];
  int cc = min(c, CAP);
  int mx = max(cc, __shfl_xor(cc, 32, 64));
  int last = max(cc - 1, 0);
  float s0=0.f, s1=0.f, s2=0.f, s3=0.f;
  for (int e=0; e<mx; e+=8){
    int i0 = min(e+0,last), i1 = min(e+1,last), i2 = min(e+2,last), i3 = min(e+3,last);
    int i4 = min(e+4,last), i5 = min(e+5,last), i6 = min(e+6,last), i7 = min(e+7,last);
    uint32_t p0 = base[i0], p1 = base[i1], p2 = base[i2], p3 = base[i3];
    uint32_t p4 = base[i4], p5 = base[i5], p6 = base[i6], p7 = base[i7];
    uint32_t u0 = elwf8[(p0 & 0x1FFFFu)*32u + l32];
    uint32_t u1 = elwf8[(p1 & 0x1FFFFu)*32u + l32];
    uint32_t u2 = elwf8[(p2 & 0x1FFFFu)*32u + l32];
    uint32_t u3 = elwf8[(p3 & 0x1FFFFu)*32u + l32];
    uint32_t u4 = elwf8[(p4 & 0x1FFFFu)*32u + l32];
    uint32_t u5 = elwf8[(p5 & 0x1FFFFu)*32u + l32];
    uint32_t u6 = elwf8[(p6 & 0x1FFFFu)*32u + l32];
    uint32_t u7 = elwf8[(p7 & 0x1FFFFu)*32u + l32];
    float w0 = (e+0 < cc) ? __uint_as_float((p0 >> 17) << 16) : 0.f;
    float w1 = (e+1 < cc) ? __uint_as_float((p1 >> 17) << 16) : 0.f;
    float w2 = (e+2 < cc) ? __uint_as_float((p2 >> 17) << 16) : 0.f;
    float w3 = (e+3 < cc) ? __uint_as_float((p3 >> 17) << 16) : 0.f;
    float w4 = (e+4 < cc) ? __uint_as_float((p4 >> 17) << 16) : 0.f;
    float w5 = (e+5 < cc) ? __uint_as_float((p5 >> 17) << 16) : 0.f;
    float w6 = (e+6 < cc) ? __uint_as_float((p6 >> 17) << 16) : 0.f;
    float w7 = (e+7 < cc) ? __uint_as_float((p7 >> 17) << 16) : 0.f;
    f32x2 a0 = __builtin_amdgcn_cvt_pk_f32_fp8((int)u0, false);
    f32x2 b0 = __builtin_amdgcn_cvt_pk_f32_fp8((int)u0, true);
    f32x2 a1 = __builtin_amdgcn_cvt_pk_f32_fp8((int)u1, false);
    f32x2 b1 = __builtin_amdgcn_cvt_pk_f32_fp8((int)u1, true);
    f32x2 a2 = __builtin_amdgcn_cvt_pk_f32_fp8((int)u2, false);
    f32x2 b2 = __builtin_amdgcn_cvt_pk_f32_fp8((int)u2, true);
    f32x2 a3 = __builtin_amdgcn_cvt_pk_f32_fp8((int)u3, false);
    f32x2 b3 = __builtin_amdgcn_cvt_pk_f32_fp8((int)u3, true);
    f32x2 a4 = __builtin_amdgcn_cvt_pk_f32_fp8((int)u4, false);
    f32x2 b4 = __builtin_amdgcn_cvt_pk_f32_fp8((int)u4, true);
    f32x2 a5 = __builtin_amdgcn_cvt_pk_f32_fp8((int)u5, false);
    f32x2 b5 = __builtin_amdgcn_cvt_pk_f32_fp8((int)u5, true);
    f32x2 a6 = __builtin_amdgcn_cvt_pk_f32_fp8((int)u6, false);
    f32x2 b6 = __builtin_amdgcn_cvt_pk_f32_fp8((int)u6, true);
    f32x2 a7 = __builtin_amdgcn_cvt_pk_f32_fp8((int)u7, false);
    f32x2 b7 = __builtin_amdgcn_cvt_pk_f32_fp8((int)u7, true);
    s0 += a0.x*w0; s1 += a0.y*w0; s2 += b0.x*w0; s3 += b0.y*w0;
    s0 += a1.x*w1; s1 += a1.y*w1; s2 += b1.x*w1; s3 += b1.y*w1;
    s0 += a2.x*w2; s1 += a2.y*w2; s2 += b2.x*w2; s3 += b2.y*w2;
    s0 += a3.x*w3; s1 += a3.y*w3; s2 += b3.x*w3; s3 += b3.y*w3;
    s0 += a4.x*w4; s1 += a4.y*w4; s2 += b4.x*w4; s3 += b4.y*w4;
    s0 += a5.x*w5; s1 += a5.y*w5; s2 += b5.x*w5; s3 += b5.y*w5;
    s0 += a6.x*w6; s1 += a6.y*w6; s2 += b6.x*w6; s3 += b6.y*w6;
    s0 += a7.x*w7; s1 += a7.y*w7; s2 += b7.x*w7; s3 += b7.y*w7;
  }
  {
    int ocnt = cnt[N_NODES];
    for (int i = 0; i < ocnt; ++i){
      int4 o = ovf[i];
      if (o.y == node){
        float wvv = __int_as_float(o.z);
        uint32_t u = elwf8[(uint32_t)o.x*32u + l32];
        f32x2 fa = __builtin_amdgcn_cvt_pk_f32_fp8((int)u, false);
        f32x2 fb = __builtin_amdgcn_cvt_pk_f32_fp8((int)u, true);
        s0 += fa.x*wvv; s1 += fa.y*wvv; s2 += fb.x*wvv; s3 += fb.y*wvv;
      }
    }
  }
  float4 bb = ((const float4*)elb)[l32];
  s0 += bb.x; s1 += bb.y; s2 += bb.z; s3 += bb.w;
  uint32_t oa = bf16rne(s0) | (bf16rne(s1) << 16);
  uint32_t ob = bf16rne(s2) | (bf16rne(s3) << 16);
  *(uint2*)&accbb[(size_t)node*(HD/2) + 2*l32] = make_uint2(oa, ob);
}

// ---------------- fused node chain, 64-row tile (32KB LDS -> 4 blocks/CU) ----------
// 8 waves = 8 col-tiles of 16 (phases 1-3); phase 4: 4 row-tiles x 2 col-halves.
__global__ __launch_bounds__(512, 8) void k_fused(
    const uint32_t* __restrict__ accbb, const float* __restrict__ x,
    const uint32_t* __restrict__ B1pk, const uint32_t* __restrict__ B2pk,
    const uint32_t* __restrict__ B3pk, const uint32_t* __restrict__ B4pk,
    const float* __restrict__ biasv, const float* __restrict__ sb0,
    const float* __restrict__ sb1, float* __restrict__ outp){
  __shared__ uint32_t lds[8192];                 // 32 KB
  short* sHi = (short*)lds;                      // [64][128] bf16
  short* sLo = sHi + 8192;
  const int tid = threadIdx.x;
  const int lane = tid & 63, wid = tid >> 6;
  const int l15 = lane & 15, l4 = lane >> 4;
  const int row0 = blockIdx.x * 64;

  // ---- stage acc (bf16, hi only): 64 rows x 16 uint4 slots ----
  #pragma unroll
  for (int p=0;p<2;p++){
    int idx = tid + p*512;
    int r = idx >> 4, slot = idx & 15;
    uint4 v = make_uint4(0,0,0,0);
    if (row0 + r < N_NODES) v = ((const uint4*)accbb)[(size_t)(row0+r)*16 + slot];
    *(uint4*)&sHi[r*128 + ((slot ^ (r & 15)) << 3)] = v;
  }
  __syncthreads();

  // ---- phase 1: acc @ (I+cat1), hi only; wave = 16-col tile wid ----
  f32x4 acc[4];
  #pragma unroll
  for (int rt=0;rt<4;rt++) acc[rt] = (f32x4){0.f,0.f,0.f,0.f};
  #pragma unroll
  for (int kt=0;kt<4;kt++){
    int aslot = ((kt*4 + l4) ^ l15) << 3;
    bf16x8 b0 = ((const bf16x8*)B1pk)[(wid*4 + kt)*64 + lane];
    #pragma unroll
    for (int rt=0;rt<4;rt++){
      bf16x8 a = *(const bf16x8*)&sHi[(rt*16 + l15)*128 + aslot];
      acc[rt] = __builtin_amdgcn_mfma_f32_16x16x32_bf16(a, b0, acc[rt], 0,0,0);
    }
  }
  __syncthreads();

  // ---- stage x (f32 -> hi/lo): 64 rows x 32 halves ----
  #pragma unroll
  for (int p=0;p<4;p++){
    int idx = tid + p*512;
    int r = idx >> 5, half = idx & 31;
    int slot = half >> 1, h4 = (half & 1) * 4;
    float4 v = make_float4(0.f,0.f,0.f,0.f);
    if (row0 + r < N_NODES) v = ((const float4*)x)[(size_t)(row0+r)*32 + half];
    uint hx = bf16rne(v.x), hy = bf16rne(v.y), hz = bf16rne(v.z), hw = bf16rne(v.w);
    uint lx = bf16rne(v.x - __uint_as_float(hx<<16));
    uint ly = bf16rne(v.y - __uint_as_float(hy<<16));
    uint lz = bf16rne(v.z - __uint_as_float(hz<<16));
    uint lw = bf16rne(v.w - __uint_as_float(hw<<16));
    int base = r*128 + ((slot ^ (r & 15)) << 3) + h4;
    *(uint2*)&sHi[base] = make_uint2(hx | (hy<<16), hz | (hw<<16));
    *(uint2*)&sLo[base] = make_uint2(lx | (ly<<16), lz | (lw<<16));
  }
  __syncthreads();

  // ---- phase 2: + x @ M2 (hi+lo) ----
  #pragma unroll
  for (int kt=0;kt<4;kt++){
    int aslot = ((kt*4 + l4) ^ l15) << 3;
    bf16x8 b0 = ((const bf16x8*)B2pk)[(wid*4 + kt)*64 + lane];
    #pragma unroll
    for (int rt=0;rt<4;rt++){
      int abase = (rt*16 + l15)*128 + aslot;
      bf16x8 ah = *(const bf16x8*)&sHi[abase];
      bf16x8 al = *(const bf16x8*)&sLo[abase];
      acc[rt] = __builtin_amdgcn_mfma_f32_16x16x32_bf16(ah, b0, acc[rt], 0,0,0);
      acc[rt] = __builtin_amdgcn_mfma_f32_16x16x32_bf16(al, b0, acc[rt], 0,0,0);
    }
  }
  __syncthreads();

  // ---- epilogue p2: +biasv, lrelu, write out2 hi/lo ----
  {
    int col = wid*16 + l15;
    float bb = biasv[col];
    int slotE = (col >> 3), elem = col & 7;
    #pragma unroll
    for (int rt=0;rt<4;rt++)
      #pragma unroll
      for (int rg=0;rg<4;rg++){
        int r = rt*16 + l4*4 + rg;
        float v = lrelu(acc[rt][rg] + bb);
        uint h = bf16rne(v);
        uint l = bf16rne(v - __uint_as_float(h<<16));
        int sa = r*128 + ((slotE ^ (r & 15)) << 3) + elem;
        sHi[sa] = (short)h; sLo[sa] = (short)l;
      }
  }
  __syncthreads();

  // ---- phase 3: out2 @ W0T (hi+lo) ----
  #pragma unroll
  for (int rt=0;rt<4;rt++) acc[rt] = (f32x4){0.f,0.f,0.f,0.f};
  #pragma unroll
  for (int kt=0;kt<4;kt++){
    int aslot = ((kt*4 + l4) ^ l15) << 3;
    bf16x8 b0 = ((const bf16x8*)B3pk)[(wid*4 + kt)*64 + lane];
    #pragma unroll
    for (int rt=0;rt<4;rt++){
      int abase = (rt*16 + l15)*128 + aslot;
      bf16x8 ah = *(const bf16x8*)&sHi[abase];
      bf16x8 al = *(const bf16x8*)&sLo[abase];
      acc[rt] = __builtin_amdgcn_mfma_f32_16x16x32_bf16(ah, b0, acc[rt], 0,0,0);
      acc[rt] = __builtin_amdgcn_mfma_f32_16x16x32_bf16(al, b0, acc[rt], 0,0,0);
    }
  }
  __syncthreads();

  // ---- epilogue p3: +sb0, lrelu, write h hi/lo ----
  {
    int col = wid*16 + l15;
    float bb = sb0[col];
    int slotE = (col >> 3), elem = col & 7;
    #pragma unroll
    for (int rt=0;rt<4;rt++)
      #pragma unroll
      for (int rg=0;rg<4;rg++){
        int r = rt*16 + l4*4 + rg;
        float v = lrelu(acc[rt][rg] + bb);
        uint h = bf16rne(v);
        uint l = bf16rne(v - __uint_as_float(h<<16));
        int sa = r*128 + ((slotE ^ (r & 15)) << 3) + elem;
        sHi[sa] = (short)h; sLo[sa] = (short)l;
      }
  }
  __syncthreads();

  // ---- phase 4: h @ W1T (64 cols); wave = row-tile (wid&3) x col-half (wid>>2) ----
  const int rt4 = wid & 3, cb = wid >> 2;
  f32x4 y[2];
  y[0] = (f32x4){0.f,0.f,0.f,0.f};
  y[1] = (f32x4){0.f,0.f,0.f,0.f};
  #pragma unroll
  for (int kt=0;kt<4;kt++){
    int abase = (rt4*16 + l15)*128 + (((kt*4 + l4) ^ l15) << 3);
    bf16x8 ah = *(const bf16x8*)&sHi[abase];
    bf16x8 al = *(const bf16x8*)&sLo[abase];
    #pragma unroll
    for (int ct=0;ct<2;ct++){
      bf16x8 b = ((const bf16x8*)B4pk)[((cb*2+ct)*4 + kt)*64 + lane];
      y[ct] = __builtin_amdgcn_mfma_f32_16x16x32_bf16(ah, b, y[ct], 0,0,0);
      y[ct] = __builtin_amdgcn_mfma_f32_16x16x32_bf16(al, b, y[ct], 0,0,0);
    }
  }
  __syncthreads();

  float* sOut = (float*)lds;                    // [64][64] f32 = 16 KB
  #pragma unroll
  for (int ct=0;ct<2;ct++){
    int col = (cb*2+ct)*16 + l15;
    float bb = sb1[col];
    #pragma unroll
    for (int rg=0;rg<4;rg++){
      int r = rt4*16 + l4*4 + rg;
      sOut[r*OUTC + col] = lrelu(y[ct][rg] + bb);
    }
  }
  __syncthreads();
  #pragma unroll
  for (int p=0;p<2;p++){
    int o = tid + p*512;                        // 1024 float4 = 64 x 64 f32
    int r = o >> 4;
    if (row0 + r < N_NODES)
      ((float4*)outp)[(size_t)(row0+r)*16 + (o & 15)] = ((const float4*)sOut)[o];
  }
}

extern "C" void kernel_launch(void* const* d_in, const int* in_sizes, int n_in,
                              void* d_out, int out_size, void* d_ws, size_t ws_size,
                              hipStream_t stream){
  const float* x      = (const float*)d_in[0];
  const int*   ei     = (const int*)d_in[1];
  const float* ew     = (const float*)d_in[2];
  const float* w      = (const float*)d_in[3];
  const float* elw    = (const float*)d_in[4];
  const float* elb    = (const float*)d_in[5];
  const float* node_w = (const float*)d_in[6];
  const float* node_b = (const float*)d_in[7];
  const float* cat1_w = (const float*)d_in[8];
  const float* cat1_b = (const float*)d_in[9];
  const float* cat2_w = (const float*)d_in[10];
  const float* cat2_b = (const float*)d_in[11];
  const float* a0w    = (const float*)d_in[12];
  const float* a0b    = (const float*)d_in[13];
  const float* syn0_w = (const float*)d_in[14];
  const float* syn0_b = (const float*)d_in[15];
  const float* a1w    = (const float*)d_in[16];
  const float* a1b    = (const float*)d_in[17];
  const float* syn1_w = (const float*)d_in[18];
  const float* syn1_b = (const float*)d_in[19];
  float* outp = (float*)d_out;

  uint32_t* wsu = (uint32_t*)d_ws;
  uint32_t* accbb = wsu;                                   // N*64 u32 (25.6MB)
  int2*     epair = (int2*)accbb;                          // ALIAS (19.2MB), dead before gather
  uint32_t* elwf8 = accbb + (size_t)N_NODES*(HD/2);        // N*32 u32 (12.8MB)
  uint32_t* eslot = elwf8 + (size_t)N_NODES*(HD/4);        // N*CAP u32 (12.8MB)
  float* st0    = (float*)(eslot + (size_t)N_NODES*CAP);   // 2560
  float* st1    = st0 + 2560;                              // 1920
  float* M2     = st1 + 1920;                              // 128*128
  float* biasv  = M2 + HD*HD;                              // 128
  float* W0T    = biasv + HD;                              // 128*128
  float* W1T    = W0T + HD*HD;                             // 128*64
  uint32_t* B1pk = (uint32_t*)(W1T + HD*OUTC);             // 8192 u32
  uint32_t* B2pk = B1pk + 8192;
  uint32_t* B3pk = B2pk + 8192;
  uint32_t* B4pk = B3pk + 8192;                            // 4096 u32
  int*   cnt    = (int*)(B4pk + 4096);                     // N+1 (last = ovf count)
  int*   bcur   = cnt + N_NODES + 1;                       // NBUCK
  int4*  ovf    = (int4*)(((uintptr_t)(bcur + NBUCK) + 15) & ~(uintptr_t)15);

  hipMemsetAsync(cnt, 0, (N_NODES+1)*sizeof(int), stream);
  k_binit<<<(NBUCK+255)/256, 256, 0, stream>>>(bcur);
  k_cvt<<<(N_NODES*(HD/4)+255)/256, 256, 0, stream>>>(elw, elwf8);
  k_styles<<<(2560+1920+255)/256, 256, 0, stream>>>(w, a0w, a0b, a1w, a1b, st0, st1);
  k_wmod<<<HD, HD, 0, stream>>>(st0, syn0_w, W0T, HD);
  k_wmod<<<OUTC, HD, 0, stream>>>(st1, syn1_w, W1T, OUTC);
  k_m2bias<<<HD+1, HD, 0, stream>>>(node_w, node_b, cat2_w, cat1_b, cat2_b, M2, biasv);
  k_pack<<<32, 64, 0, stream>>>(cat1_w, HD, HD, 1, B1pk);
  k_pack<<<32, 64, 0, stream>>>(M2,    HD, HD, 0, B2pk);
  k_pack<<<32, 64, 0, stream>>>(W0T,   HD, HD, 0, B3pk);
  k_pack<<<16, 64, 0, stream>>>(W1T,   HD, OUTC, 0, B4pk);
  k_bucketize<<<NCH, 256, 0, stream>>>(ei, ew, bcur, epair, cnt, ovf);
  k_slotfill<<<NBUCK, 256, 0, stream>>>(bcur, epair, cnt, eslot, ovf);
  k_gather<<<((N_NODES/2)*64+255)/256, 256, 0, stream>>>(cnt, eslot, elwf8, elb, ovf, accbb);
  k_fused<<<(N_NODES+63)/64, 512, 0, stream>>>(accbb, x, B1pk, B2pk, B3pk, B4pk,
                                               biasv, syn0_b, syn1_b, outp);
}

// Round 21
// 186.803 us; speedup vs baseline: 1.5220x; 1.0014x over previous
//
#include <hip/hip_runtime.h>
#include <cstdint>
#include <cstddef>

#define N_NODES 100000
#define N_EDGES 1600000
#define HD 128
#define OUTC 64
#define WDIM 512
#define RANKK 10
#define SLOPE 0.01f
#define CAP 32
#define NBUCK ((N_NODES + 255)/256)          // 391 buckets of 256 nodes
#define BCAP 6144                             // entries per bucket region (mean 4096)
#define CHUNK 2048
#define NCH ((N_EDGES + CHUNK - 1)/CHUNK)     // 782

typedef __attribute__((ext_vector_type(8))) short bf16x8;
typedef __attribute__((ext_vector_type(4))) float f32x4;
typedef __attribute__((ext_vector_type(2))) float f32x2;

static __device__ __forceinline__ float lrelu(float v){ return v >= 0.f ? v : SLOPE*v; }
static __device__ __forceinline__ uint32_t bf16rne(float f){
  uint32_t b = __float_as_uint(f);
  return (b + 0x7FFFu + ((b >> 16) & 1u)) >> 16;
}

// ---------------- styles ----------------
__global__ void k_styles(const float* __restrict__ w,
                         const float* __restrict__ a0w, const float* __restrict__ a0b,
                         const float* __restrict__ a1w, const float* __restrict__ a1b,
                         float* __restrict__ st0, float* __restrict__ st1){
  int j = blockIdx.x*blockDim.x + threadIdx.x;
  if (j < 2560){
    float s = a0b[j];
    for (int k=0;k<WDIM;k++) s += w[k]*a0w[k*2560 + j];
    st0[j] = s;
  } else if (j < 2560+1920){
    int jj = j - 2560;
    float s = a1b[jj];
    for (int k=0;k<WDIM;k++) s += w[WDIM + k]*a1w[k*1920 + jj];
    st1[jj] = s;
  }
}

// ---------------- modulated + row-normalized weight, stored TRANSPOSED: wt[k][n] ----
__global__ void k_wmod(const float* __restrict__ st, const float* __restrict__ wgt,
                       float* __restrict__ wt, int c_out){
  int o = blockIdx.x, i = threadIdx.x;
  float mod = 0.f;
  #pragma unroll
  for (int r=0;r<RANKK;r++) mod += st[o*RANKK + r] * st[c_out*RANKK + r*HD + i];
  mod *= 0.31622776601683794f;
  float wv = wgt[o*HD + i] * (mod + 1.f);
  float sq = wv*wv;
  #pragma unroll
  for (int d=1; d<64; d<<=1) sq += __shfl_xor(sq, d, 64);
  __shared__ float red[2];
  if ((i & 63) == 0) red[i>>6] = sq;
  __syncthreads();
  float norm = sqrtf(red[0] + red[1]) + 1e-8f;
  wt[i*c_out + o] = wv / norm;
}

// ---------------- M2 = node_w @ (I + cat2) ; biasv = cat1_b + cat2_b + node_b@(I+cat2)
__global__ void k_m2bias(const float* __restrict__ node_w, const float* __restrict__ node_b,
                         const float* __restrict__ cat2_w, const float* __restrict__ cat1_b,
                         const float* __restrict__ cat2_b,
                         float* __restrict__ M2, float* __restrict__ biasv){
  int i = threadIdx.x;
  int k = blockIdx.x;
  if (k < HD){
    float s = node_w[k*HD + i];
    for (int j=0;j<HD;j++) s += node_w[k*HD + j]*cat2_w[j*HD + i];
    M2[k*HD + i] = s;
  } else {
    float s = cat1_b[i] + cat2_b[i] + node_b[i];
    for (int j=0;j<HD;j++) s += node_b[j]*cat2_w[j*HD + i];
    biasv[i] = s;
  }
}

// ---------------- pack B [K][Ncols] f32 -> bf16 MFMA fragments ----------------
__global__ void k_pack(const float* __restrict__ src, int K, int Ncols, int addI,
                       uint32_t* __restrict__ dst){
  int KTn = K >> 5;
  int kt = blockIdx.x % KTn, nt = blockIdx.x / KTn;
  int lane = threadIdx.x;
  int col = nt*16 + (lane & 15);
  uint32_t o[4];
  #pragma unroll
  for (int jj=0;jj<4;jj++){
    int k0 = kt*32 + (lane>>4)*8 + 2*jj;
    float v0 = src[(size_t)k0*Ncols + col]     + ((addI && k0   == col) ? 1.f : 0.f);
    float v1 = src[(size_t)(k0+1)*Ncols + col] + ((addI && k0+1 == col) ? 1.f : 0.f);
    o[jj] = bf16rne(v0) | (bf16rne(v1) << 16);
  }
  ((uint4*)dst)[blockIdx.x*64 + lane] = make_uint4(o[0], o[1], o[2], o[3]);
}

// ---------------- elw f32 -> fp8 e4m3 packed (4 per u32) ----------------
__global__ void k_cvt(const float* __restrict__ elw, uint32_t* __restrict__ elwf8){
  int i = blockIdx.x*blockDim.x + threadIdx.x;
  if (i < N_NODES*(HD/4)){
    float4 v = ((const float4*)elw)[i];
    int r = 0;
    r = __builtin_amdgcn_cvt_pk_fp8_f32(v.x, v.y, r, false);
    r = __builtin_amdgcn_cvt_pk_fp8_f32(v.z, v.w, r, true);
    elwf8[i] = (uint32_t)r;
  }
}

// ---------------- bcur init ----------------
__global__ void k_binit(int* __restrict__ bcur){
  int b = blockIdx.x*blockDim.x + threadIdx.x;
  if (b < NBUCK) bcur[b] = b*BCAP;
}

// ---------------- P1: chunk -> LDS counting sort by bucket -> grouped flush ----------
__global__ __launch_bounds__(256) void k_bucketize(const int* __restrict__ ei,
                                                   const float* __restrict__ ew,
                                                   int* __restrict__ bcur,
                                                   int2* __restrict__ epair,
                                                   int* __restrict__ cnt,
                                                   int4* __restrict__ ovf){
  __shared__ int2 ed[CHUNK];
  __shared__ unsigned short bkt[CHUNK];
  __shared__ unsigned short sidx[CHUNK];
  __shared__ int sa[512], sb[512];
  __shared__ int off[NBUCK], pcur[NBUCK], gbase[NBUCK];
  const int tid = threadIdx.x;
  const int e0 = blockIdx.x * CHUNK;
  const int ne = min(CHUNK, N_EDGES - e0);

  sa[tid] = 0; sa[tid+256] = 0;
  __syncthreads();
  for (int i=tid; i<ne; i+=256){
    int src = ei[e0+i], dst = ei[N_EDGES+e0+i];
    ed[i]  = make_int2(src | ((dst & 255) << 17), __float_as_int(ew[e0+i]));
    int b = dst >> 8;
    bkt[i] = (unsigned short)b;
    atomicAdd(&sa[b], 1);
  }
  __syncthreads();
  int c0 = sa[tid], c1 = sa[tid+256];
  int* cur = sa; int* oth = sb;
  for (int d=1; d<512; d<<=1){
    int v0 = cur[tid]     + (tid     >= d ? cur[tid-d]     : 0);
    int v1 = cur[tid+256] + (tid+256 >= d ? cur[tid+256-d] : 0);
    oth[tid] = v0; oth[tid+256] = v1;
    __syncthreads();
    int* t_ = cur; cur = oth; oth = t_;
  }
  off[tid] = cur[tid] - c0;  pcur[tid] = cur[tid] - c0;
  if (tid+256 < NBUCK){ off[tid+256] = cur[tid+256] - c1; pcur[tid+256] = cur[tid+256] - c1; }
  __syncthreads();
  int rot = (blockIdx.x * 73) % NBUCK;
  for (int k=tid; k<NBUCK; k+=256){
    int b = k + rot; if (b >= NBUCK) b -= NBUCK;
    int cb = cur[b] - off[b];
    if (cb > 0) gbase[b] = atomicAdd(&bcur[b], cb);
  }
  __syncthreads();
  for (int i=tid; i<ne; i+=256){
    int s = atomicAdd(&pcur[bkt[i]], 1);
    sidx[s] = (unsigned short)i;
  }
  __syncthreads();
  for (int j=tid; j<ne; j+=256){
    int i = sidx[j];
    int b = bkt[i];
    int addr = gbase[b] + (j - off[b]);
    if (addr < (b+1)*BCAP){
      epair[addr] = ed[i];
    } else {
      int oi = atomicAdd(&cnt[N_NODES], 1);
      ovf[oi] = make_int4(ed[i].x & 0x1FFFF, b*256 + ((ed[i].x>>17)&255), ed[i].y, 0);
    }
  }
}

// ---------------- P2: bucket region -> per-node slots ----------------
__global__ __launch_bounds__(256) void k_slotfill(const int* __restrict__ bcur,
                                                  const int2* __restrict__ epair,
                                                  int* __restrict__ cnt,
                                                  uint32_t* __restrict__ eslot,
                                                  int4* __restrict__ ovf){
  __shared__ int lcnt[256];
  const int tid = threadIdx.x;
  const int b = blockIdx.x;
  const int n0 = b*256;
  const int2* reg = epair + (size_t)b*BCAP;
  const int count = min(bcur[b], (b+1)*BCAP) - b*BCAP;
  lcnt[tid] = 0;
  __syncthreads();
  for (int j=tid; j<count; j+=256){
    int2 rec = reg[j];
    int ldst = (rec.x >> 17) & 255;
    int pos = atomicAdd(&lcnt[ldst], 1);
    if (pos < CAP){
      uint32_t wb = (uint32_t)rec.y;
      uint32_t wenc = ((wb + 0x8000u) >> 16) & 0x7FFFu;
      eslot[(size_t)(n0+ldst)*CAP + pos] = (uint32_t)(rec.x & 0x1FFFF) | (wenc << 17);
    } else {
      int oi = atomicAdd(&cnt[N_NODES], 1);
      ovf[oi] = make_int4(rec.x & 0x1FFFF, n0 + ldst, rec.y, 0);
    }
  }
  __syncthreads();
  if (n0 + tid < N_NODES) cnt[n0 + tid] = lcnt[tid];
}

// ---------------- gather: TWO nodes per wave, fp8 rows, pk-f32 accumulate -----------
// Full batches (both halves) run unmasked (no clamp/sel); masked batches only in
// [nf, mx). f32x2 accumulators -> v_pk_fma_f32 halves the FMA issue count.
__global__ __launch_bounds__(256) void k_gather(const int* __restrict__ cnt,
                         const uint32_t* __restrict__ eslot,
                         const uint32_t* __restrict__ elwf8, const float* __restrict__ elb,
                         const int4* __restrict__ ovf,
                         uint32_t* __restrict__ accbb){
  int wv = (blockIdx.x * blockDim.x + threadIdx.x) >> 6;
  int lane = threadIdx.x & 63;
  if (wv >= N_NODES/2) return;               // N even
  const int half = lane >> 5, l32 = lane & 31;
  const int node = wv*2 + half;
  const uint32_t* base = eslot + (size_t)node*CAP;
  int c = cnt[node];
  int cc = min(c, CAP);
  int cco = __shfl_xor(cc, 32, 64);
  int mx = max(cc, cco);
  int nf = min(cc, cco) & ~7;                // full batches for BOTH halves
  int last = max(cc - 1, 0);
  f32x2 s01 = (f32x2){0.f, 0.f};
  f32x2 s23 = (f32x2){0.f, 0.f};
  int e = 0;
  for (; e < nf; e += 8){                    // unmasked: no clamp, no sel
    uint32_t p0 = base[e],   p1 = base[e+1], p2 = base[e+2], p3 = base[e+3];
    uint32_t p4 = base[e+4], p5 = base[e+5], p6 = base[e+6], p7 = base[e+7];
    uint32_t u0 = elwf8[(p0 & 0x1FFFFu)*32u + l32];
    uint32_t u1 = elwf8[(p1 & 0x1FFFFu)*32u + l32];
    uint32_t u2 = elwf8[(p2 & 0x1FFFFu)*32u + l32];
    uint32_t u3 = elwf8[(p3 & 0x1FFFFu)*32u + l32];
    uint32_t u4 = elwf8[(p4 & 0x1FFFFu)*32u + l32];
    uint32_t u5 = elwf8[(p5 & 0x1FFFFu)*32u + l32];
    uint32_t u6 = elwf8[(p6 & 0x1FFFFu)*32u + l32];
    uint32_t u7 = elwf8[(p7 & 0x1FFFFu)*32u + l32];
    float w0 = __uint_as_float((p0 >> 17) << 16), w1 = __uint_as_float((p1 >> 17) << 16);
    float w2 = __uint_as_float((p2 >> 17) << 16), w3 = __uint_as_float((p3 >> 17) << 16);
    float w4 = __uint_as_float((p4 >> 17) << 16), w5 = __uint_as_float((p5 >> 17) << 16);
    float w6 = __uint_as_float((p6 >> 17) << 16), w7 = __uint_as_float((p7 >> 17) << 16);
    f32x2 wp;
    wp = (f32x2){w0,w0};
    s01 += __builtin_amdgcn_cvt_pk_f32_fp8((int)u0, false) * wp;
    s23 += __builtin_amdgcn_cvt_pk_f32_fp8((int)u0, true)  * wp;
    wp = (f32x2){w1,w1};
    s01 += __builtin_amdgcn_cvt_pk_f32_fp8((int)u1, false) * wp;
    s23 += __builtin_amdgcn_cvt_pk_f32_fp8((int)u1, true)  * wp;
    wp = (f32x2){w2,w2};
    s01 += __builtin_amdgcn_cvt_pk_f32_fp8((int)u2, false) * wp;
    s23 += __builtin_amdgcn_cvt_pk_f32_fp8((int)u2, true)  * wp;
    wp = (f32x2){w3,w3};
    s01 += __builtin_amdgcn_cvt_pk_f32_fp8((int)u3, false) * wp;
    s23 += __builtin_amdgcn_cvt_pk_f32_fp8((int)u3, true)  * wp;
    wp = (f32x2){w4,w4};
    s01 += __builtin_amdgcn_cvt_pk_f32_fp8((int)u4, false) * wp;
    s23 += __builtin_amdgcn_cvt_pk_f32_fp8((int)u4, true)  * wp;
    wp = (f32x2){w5,w5};
    s01 += __builtin_amdgcn_cvt_pk_f32_fp8((int)u5, false) * wp;
    s23 += __builtin_amdgcn_cvt_pk_f32_fp8((int)u5, true)  * wp;
    wp = (f32x2){w6,w6};
    s01 += __builtin_amdgcn_cvt_pk_f32_fp8((int)u6, false) * wp;
    s23 += __builtin_amdgcn_cvt_pk_f32_fp8((int)u6, true)  * wp;
    wp = (f32x2){w7,w7};
    s01 += __builtin_amdgcn_cvt_pk_f32_fp8((int)u7, false) * wp;
    s23 += __builtin_amdgcn_cvt_pk_f32_fp8((int)u7, true)  * wp;
  }
  for (; e < mx; e += 8){                    // masked batches
    int i0 = min(e+0,last), i1 = min(e+1,last), i2 = min(e+2,last), i3 = min(e+3,last);
    int i4 = min(e+4,last), i5 = min(e+5,last), i6 = min(e+6,last), i7 = min(e+7,last);
    uint32_t p0 = base[i0], p1 = base[i1], p2 = base[i2], p3 = base[i3];
    uint32_t p4 = base[i4], p5 = base[i5], p6 = base[i6], p7 = base[i7];
    uint32_t u0 = elwf8[(p0 & 0x1FFFFu)*32u + l32];
    uint32_t u1 = elwf8[(p1 & 0x1FFFFu)*32u + l32];
    uint32_t u2 = elwf8[(p2 & 0x1FFFFu)*32u + l32];
    uint32_t u3 = elwf8[(p3 & 0x1FFFFu)*32u + l32];
    uint32_t u4 = elwf8[(p4 & 0x1FFFFu)*32u + l32];
    uint32_t u5 = elwf8[(p5 & 0x1FFFFu)*32u + l32];
    uint32_t u6 = elwf8[(p6 & 0x1FFFFu)*32u + l32];
    uint32_t u7 = elwf8[(p7 & 0x1FFFFu)*32u + l32];
    float w0 = (e+0 < cc) ? __uint_as_float((p0 >> 17) << 16) : 0.f;
    float w1 = (e+1 < cc) ? __uint_as_float((p1 >> 17) << 16) : 0.f;
    float w2 = (e+2 < cc) ? __uint_as_float((p2 >> 17) << 16) : 0.f;
    float w3 = (e+3 < cc) ? __uint_as_float((p3 >> 17) << 16) : 0.f;
    float w4 = (e+4 < cc) ? __uint_as_float((p4 >> 17) << 16) : 0.f;
    float w5 = (e+5 < cc) ? __uint_as_float((p5 >> 17) << 16) : 0.f;
    float w6 = (e+6 < cc) ? __uint_as_float((p6 >> 17) << 16) : 0.f;
    float w7 = (e+7 < cc) ? __uint_as_float((p7 >> 17) << 16) : 0.f;
    f32x2 wp;
    wp = (f32x2){w0,w0};
    s01 += __builtin_amdgcn_cvt_pk_f32_fp8((int)u0, false) * wp;
    s23 += __builtin_amdgcn_cvt_pk_f32_fp8((int)u0, true)  * wp;
    wp = (f32x2){w1,w1};
    s01 += __builtin_amdgcn_cvt_pk_f32_fp8((int)u1, false) * wp;
    s23 += __builtin_amdgcn_cvt_pk_f32_fp8((int)u1, true)  * wp;
    wp = (f32x2){w2,w2};
    s01 += __builtin_amdgcn_cvt_pk_f32_fp8((int)u2, false) * wp;
    s23 += __builtin_amdgcn_cvt_pk_f32_fp8((int)u2, true)  * wp;
    wp = (f32x2){w3,w3};
    s01 += __builtin_amdgcn_cvt_pk_f32_fp8((int)u3, false) * wp;
    s23 += __builtin_amdgcn_cvt_pk_f32_fp8((int)u3, true)  * wp;
    wp = (f32x2){w4,w4};
    s01 += __builtin_amdgcn_cvt_pk_f32_fp8((int)u4, false) * wp;
    s23 += __builtin_amdgcn_cvt_pk_f32_fp8((int)u4, true)  * wp;
    wp = (f32x2){w5,w5};
    s01 += __builtin_amdgcn_cvt_pk_f32_fp8((int)u5, false) * wp;
    s23 += __builtin_amdgcn_cvt_pk_f32_fp8((int)u5, true)  * wp;
    wp = (f32x2){w6,w6};
    s01 += __builtin_amdgcn_cvt_pk_f32_fp8((int)u6, false) * wp;
    s23 += __builtin_amdgcn_cvt_pk_f32_fp8((int)u6, true)  * wp;
    wp = (f32x2){w7,w7};
    s01 += __builtin_amdgcn_cvt_pk_f32_fp8((int)u7, false) * wp;
    s23 += __builtin_amdgcn_cvt_pk_f32_fp8((int)u7, true)  * wp;
  }
  {
    int ocnt = cnt[N_NODES];
    for (int i = 0; i < ocnt; ++i){
      int4 o = ovf[i];
      if (o.y == node){
        float wvv = __int_as_float(o.z);
        uint32_t u = elwf8[(uint32_t)o.x*32u + l32];
        f32x2 wp = (f32x2){wvv, wvv};
        s01 += __builtin_amdgcn_cvt_pk_f32_fp8((int)u, false) * wp;
        s23 += __builtin_amdgcn_cvt_pk_f32_fp8((int)u, true)  * wp;
      }
    }
  }
  float4 bb = ((const float4*)elb)[l32];
  float s0 = s01.x + bb.x, s1 = s01.y + bb.y;
  float s2 = s23.x + bb.z, s3 = s23.y + bb.w;
  uint32_t oa = bf16rne(s0) | (bf16rne(s1) << 16);
  uint32_t ob = bf16rne(s2) | (bf16rne(s3) << 16);
  *(uint2*)&accbb[(size_t)node*(HD/2) + 2*l32] = make_uint2(oa, ob);
}

// ---------------- fused node chain, 64-row tile (32KB LDS -> 4 blocks/CU) ----------
__global__ __launch_bounds__(512, 8) void k_fused(
    const uint32_t* __restrict__ accbb, const float* __restrict__ x,
    const uint32_t* __restrict__ B1pk, const uint32_t* __restrict__ B2pk,
    const uint32_t* __restrict__ B3pk, const uint32_t* __restrict__ B4pk,
    const float* __restrict__ biasv, const float* __restrict__ sb0,
    const float* __restrict__ sb1, float* __restrict__ outp){
  __shared__ uint32_t lds[8192];                 // 32 KB
  short* sHi = (short*)lds;                      // [64][128] bf16
  short* sLo = sHi + 8192;
  const int tid = threadIdx.x;
  const int lane = tid & 63, wid = tid >> 6;
  const int l15 = lane & 15, l4 = lane >> 4;
  const int row0 = blockIdx.x * 64;

  #pragma unroll
  for (int p=0;p<2;p++){
    int idx = tid + p*512;
    int r = idx >> 4, slot = idx & 15;
    uint4 v = make_uint4(0,0,0,0);
    if (row0 + r < N_NODES) v = ((const uint4*)accbb)[(size_t)(row0+r)*16 + slot];
    *(uint4*)&sHi[r*128 + ((slot ^ (r & 15)) << 3)] = v;
  }
  __syncthreads();

  f32x4 acc[4];
  #pragma unroll
  for (int rt=0;rt<4;rt++) acc[rt] = (f32x4){0.f,0.f,0.f,0.f};
  #pragma unroll
  for (int kt=0;kt<4;kt++){
    int aslot = ((kt*4 + l4) ^ l15) << 3;
    bf16x8 b0 = ((const bf16x8*)B1pk)[(wid*4 + kt)*64 + lane];
    #pragma unroll
    for (int rt=0;rt<4;rt++){
      bf16x8 a = *(const bf16x8*)&sHi[(rt*16 + l15)*128 + aslot];
      acc[rt] = __builtin_amdgcn_mfma_f32_16x16x32_bf16(a, b0, acc[rt], 0,0,0);
    }
  }
  __syncthreads();

  #pragma unroll
  for (int p=0;p<4;p++){
    int idx = tid + p*512;
    int r = idx >> 5, half = idx & 31;
    int slot = half >> 1, h4 = (half & 1) * 4;
    float4 v = make_float4(0.f,0.f,0.f,0.f);
    if (row0 + r < N_NODES) v = ((const float4*)x)[(size_t)(row0+r)*32 + half];
    uint hx = bf16rne(v.x), hy = bf16rne(v.y), hz = bf16rne(v.z), hw = bf16rne(v.w);
    uint lx = bf16rne(v.x - __uint_as_float(hx<<16));
    uint ly = bf16rne(v.y - __uint_as_float(hy<<16));
    uint lz = bf16rne(v.z - __uint_as_float(hz<<16));
    uint lw = bf16rne(v.w - __uint_as_float(hw<<16));
    int base = r*128 + ((slot ^ (r & 15)) << 3) + h4;
    *(uint2*)&sHi[base] = make_uint2(hx | (hy<<16), hz | (hw<<16));
    *(uint2*)&sLo[base] = make_uint2(lx | (ly<<16), lz | (lw<<16));
  }
  __syncthreads();

  #pragma unroll
  for (int kt=0;kt<4;kt++){
    int aslot = ((kt*4 + l4) ^ l15) << 3;
    bf16x8 b0 = ((const bf16x8*)B2pk)[(wid*4 + kt)*64 + lane];
    #pragma unroll
    for (int rt=0;rt<4;rt++){
      int abase = (rt*16 + l15)*128 + aslot;
      bf16x8 ah = *(const bf16x8*)&sHi[abase];
      bf16x8 al = *(const bf16x8*)&sLo[abase];
      acc[rt] = __builtin_amdgcn_mfma_f32_16x16x32_bf16(ah, b0, acc[rt], 0,0,0);
      acc[rt] = __builtin_amdgcn_mfma_f32_16x16x32_bf16(al, b0, acc[rt], 0,0,0);
    }
  }
  __syncthreads();

  {
    int col = wid*16 + l15;
    float bb = biasv[col];
    int slotE = (col >> 3), elem = col & 7;
    #pragma unroll
    for (int rt=0;rt<4;rt++)
      #pragma unroll
      for (int rg=0;rg<4;rg++){
        int r = rt*16 + l4*4 + rg;
        float v = lrelu(acc[rt][rg] + bb);
        uint h = bf16rne(v);
        uint l = bf16rne(v - __uint_as_float(h<<16));
        int sa = r*128 + ((slotE ^ (r & 15)) << 3) + elem;
        sHi[sa] = (short)h; sLo[sa] = (short)l;
      }
  }
  __syncthreads();

  #pragma unroll
  for (int rt=0;rt<4;rt++) acc[rt] = (f32x4){0.f,0.f,0.f,0.f};
  #pragma unroll
  for (int kt=0;kt<4;kt++){
    int aslot = ((kt*4 + l4) ^ l15) << 3;
    bf16x8 b0 = ((const bf16x8*)B3pk)[(wid*4 + kt)*64 + lane];
    #pragma unroll
    for (int rt=0;rt<4;rt++){
      int abase = (rt*16 + l15)*128 + aslot;
      bf16x8 ah = *(const bf16x8*)&sHi[abase];
      bf16x8 al = *(const bf16x8*)&sLo[abase];
      acc[rt] = __builtin_amdgcn_mfma_f32_16x16x32_bf16(ah, b0, acc[rt], 0,0,0);
      acc[rt] = __builtin_amdgcn_mfma_f32_16x16x32_bf16(al, b0, acc[rt], 0,0,0);
    }
  }
  __syncthreads();

  {
    int col = wid*16 + l15;
    float bb = sb0[col];
    int slotE = (col >> 3), elem = col & 7;
    #pragma unroll
    for (int rt=0;rt<4;rt++)
      #pragma unroll
      for (int rg=0;rg<4;rg++){
        int r = rt*16 + l4*4 + rg;
        float v = lrelu(acc[rt][rg] + bb);
        uint h = bf16rne(v);
        uint l = bf16rne(v - __uint_as_float(h<<16));
        int sa = r*128 + ((slotE ^ (r & 15)) << 3) + elem;
        sHi[sa] = (short)h; sLo[sa] = (short)l;
      }
  }
  __syncthreads();

  const int rt4 = wid & 3, cb = wid >> 2;
  f32x4 y[2];
  y[0] = (f32x4){0.f,0.f,0.f,0.f};
  y[1] = (f32x4){0.f,0.f,0.f,0.f};
  #pragma unroll
  for (int kt=0;kt<4;kt++){
    int abase = (rt4*16 + l15)*128 + (((kt*4 + l4) ^ l15) << 3);
    bf16x8 ah = *(const bf16x8*)&sHi[abase];
    bf16x8 al = *(const bf16x8*)&sLo[abase];
    #pragma unroll
    for (int ct=0;ct<2;ct++){
      bf16x8 b = ((const bf16x8*)B4pk)[((cb*2+ct)*4 + kt)*64 + lane];
      y[ct] = __builtin_amdgcn_mfma_f32_16x16x32_bf16(ah, b, y[ct], 0,0,0);
      y[ct] = __builtin_amdgcn_mfma_f32_16x16x32_bf16(al, b, y[ct], 0,0,0);
    }
  }
  __syncthreads();

  float* sOut = (float*)lds;
  #pragma unroll
  for (int ct=0;ct<2;ct++){
    int col = (cb*2+ct)*16 + l15;
    float bb = sb1[col];
    #pragma unroll
    for (int rg=0;rg<4;rg++){
      int r = rt4*16 + l4*4 + rg;
      sOut[r*OUTC + col] = lrelu(y[ct][rg] + bb);
    }
  }
  __syncthreads();
  #pragma unroll
  for (int p=0;p<2;p++){
    int o = tid + p*512;
    int r = o >> 4;
    if (row0 + r < N_NODES)
      ((float4*)outp)[(size_t)(row0+r)*16 + (o & 15)] = ((const float4*)sOut)[o];
  }
}

extern "C" void kernel_launch(void* const* d_in, const int* in_sizes, int n_in,
                              void* d_out, int out_size, void* d_ws, size_t ws_size,
                              hipStream_t stream){
  const float* x      = (const float*)d_in[0];
  const int*   ei     = (const int*)d_in[1];
  const float* ew     = (const float*)d_in[2];
  const float* w      = (const float*)d_in[3];
  const float* elw    = (const float*)d_in[4];
  const float* elb    = (const float*)d_in[5];
  const float* node_w = (const float*)d_in[6];
  const float* node_b = (const float*)d_in[7];
  const float* cat1_w = (const float*)d_in[8];
  const float* cat1_b = (const float*)d_in[9];
  const float* cat2_w = (const float*)d_in[10];
  const float* cat2_b = (const float*)d_in[11];
  const float* a0w    = (const float*)d_in[12];
  const float* a0b    = (const float*)d_in[13];
  const float* syn0_w = (const float*)d_in[14];
  const float* syn0_b = (const float*)d_in[15];
  const float* a1w    = (const float*)d_in[16];
  const float* a1b    = (const float*)d_in[17];
  const float* syn1_w = (const float*)d_in[18];
  const float* syn1_b = (const float*)d_in[19];
  float* outp = (float*)d_out;

  uint32_t* wsu = (uint32_t*)d_ws;
  uint32_t* accbb = wsu;                                   // N*64 u32 (25.6MB)
  int2*     epair = (int2*)accbb;                          // ALIAS (19.2MB), dead before gather
  uint32_t* elwf8 = accbb + (size_t)N_NODES*(HD/2);        // N*32 u32 (12.8MB)
  uint32_t* eslot = elwf8 + (size_t)N_NODES*(HD/4);        // N*CAP u32 (12.8MB)
  float* st0    = (float*)(eslot + (size_t)N_NODES*CAP);   // 2560
  float* st1    = st0 + 2560;                              // 1920
  float* M2     = st1 + 1920;                              // 128*128
  float* biasv  = M2 + HD*HD;                              // 128
  float* W0T    = biasv + HD;                              // 128*128
  float* W1T    = W0T + HD*HD;                             // 128*64
  uint32_t* B1pk = (uint32_t*)(W1T + HD*OUTC);             // 8192 u32
  uint32_t* B2pk = B1pk + 8192;
  uint32_t* B3pk = B2pk + 8192;
  uint32_t* B4pk = B3pk + 8192;                            // 4096 u32
  int*   cnt    = (int*)(B4pk + 4096);                     // N+1 (last = ovf count)
  int*   bcur   = cnt + N_NODES + 1;                       // NBUCK
  int4*  ovf    = (int4*)(((uintptr_t)(bcur + NBUCK) + 15) & ~(uintptr_t)15);

  hipMemsetAsync(cnt, 0, (N_NODES+1)*sizeof(int), stream);
  k_binit<<<(NBUCK+255)/256, 256, 0, stream>>>(bcur);
  k_cvt<<<(N_NODES*(HD/4)+255)/256, 256, 0, stream>>>(elw, elwf8);
  k_styles<<<(2560+1920+255)/256, 256, 0, stream>>>(w, a0w, a0b, a1w, a1b, st0, st1);
  k_wmod<<<HD, HD, 0, stream>>>(st0, syn0_w, W0T, HD);
  k_wmod<<<OUTC, HD, 0, stream>>>(st1, syn1_w, W1T, OUTC);
  k_m2bias<<<HD+1, HD, 0, stream>>>(node_w, node_b, cat2_w, cat1_b, cat2_b, M2, biasv);
  k_pack<<<32, 64, 0, stream>>>(cat1_w, HD, HD, 1, B1pk);
  k_pack<<<32, 64, 0, stream>>>(M2,    HD, HD, 0, B2pk);
  k_pack<<<32, 64, 0, stream>>>(W0T,   HD, HD, 0, B3pk);
  k_pack<<<16, 64, 0, stream>>>(W1T,   HD, OUTC, 0, B4pk);
  k_bucketize<<<NCH, 256, 0, stream>>>(ei, ew, bcur, epair, cnt, ovf);
  k_slotfill<<<NBUCK, 256, 0, stream>>>(bcur, epair, cnt, eslot, ovf);
  k_gather<<<((N_NODES/2)*64+255)/256, 256, 0, stream>>>(cnt, eslot, elwf8, elb, ovf, accbb);
  k_fused<<<(N_NODES+63)/64, 512, 0, stream>>>(accbb, x, B1pk, B2pk, B3pk, B4pk,
                                               biasv, syn0_b, syn1_b, outp);
}